// Round 12
// baseline (161.416 us; speedup 1.0000x reference)
//
#include <hip/hip_runtime.h>
#include <stdint.h>

// MultiHeadedAttention: B=2,S=2048,D=1024,H=16,HD=64
// R12 = R11 with cvt3 DELETED: gemm_qkv stages A directly from the f32
// q/k/v inputs (reg-staged: f32x4 loads -> v_cvt_pk_bf16_f32 -> swizzled
// ds_write_b128; RNE rounding identical to cvt3). pack_wo folded into
// pack_w4 (z=3). attn / attn_norm / gemm_out identical to R11.
// Workspace map (MB): 0-8 Op0, 8-16 Op1, 16-24 x, 24-30 w3, 30-32 wo,
// 32-40 Qp, 40-48 Kp, 48-56 Vp, 56+ lacc(512KB)+flags(4KB)

typedef __bf16 bf16x8 __attribute__((ext_vector_type(8)));
typedef __bf16 bf16x4 __attribute__((ext_vector_type(4)));
typedef float f32x4 __attribute__((ext_vector_type(4)));
typedef float f32x16 __attribute__((ext_vector_type(16)));
typedef unsigned u32x4 __attribute__((ext_vector_type(4)));

static constexpr float L2E  = 1.4426950408889634f;
static constexpr float QSCL = 0.18033688011112042f;   // 0.125 * log2(e)
static constexpr float GELC = -2.4554669595930157f;   // -1.702 * log2(e)

__device__ __forceinline__ void async_load16(const void* g, void* l) {
    __builtin_amdgcn_global_load_lds(
        (const __attribute__((address_space(1))) unsigned int*)(uintptr_t)g,
        (__attribute__((address_space(3))) unsigned int*)(unsigned int)(uintptr_t)l,
        16, 0, 0);
}

// Stage ROWS x 64-bf16 tile into LDS, phys = row*128 + (kb ^ ((row&7)<<4)).
template <int ROWS>
__device__ __forceinline__ void stage_tile(const __bf16* g, int ld, __bf16* lds, int tid) {
#pragma unroll
    for (int r = 0; r < ROWS / 32; ++r) {
        int p = r * 4096 + tid * 16;
        int row = p >> 7;
        int kbp = p & 127;
        int kbl = kbp ^ ((row & 7) << 4);
        async_load16((const char*)(g + (size_t)row * ld) + kbl,
                     (char*)lds + (p & ~1023));
    }
}

__device__ __forceinline__ bf16x8 lds_frag(const __bf16* base, int row, int kb) {
    return *(const bf16x8*)((const char*)base + (row << 7) + (kb ^ ((row & 7) << 4)));
}

__device__ __forceinline__ unsigned cvtpk(float a, float b) {
    unsigned d;
    asm("v_cvt_pk_bf16_f32 %0, %1, %2" : "=v"(d) : "v"(a), "v"(b));
    return d;
}
__device__ __forceinline__ void pswap(unsigned& a, unsigned& b) {
    asm("v_permlane32_swap_b32 %0, %1" : "+v"(a), "+v"(b));
}

// Stage 128x64 f32 tile -> bf16 swizzled LDS via registers (RNE via cvt_pk).
// Thread t, pass p: row = p*32 + t/8, 8 cols at (t&7)*8.
__device__ __forceinline__ void stage_a_f32(const float* g, __bf16* lds, int tid) {
    int rsub = tid >> 3;
    int c8 = (tid & 7) * 8;
#pragma unroll
    for (int pass = 0; pass < 4; ++pass) {
        int row = pass * 32 + rsub;
        const float* src = g + (size_t)row * 1024 + c8;
        f32x4 a = *(const f32x4*)src;
        f32x4 b = *(const f32x4*)(src + 4);
        u32x4 pk;
        pk[0] = cvtpk(a[0], a[1]);
        pk[1] = cvtpk(a[2], a[3]);
        pk[2] = cvtpk(b[0], b[1]);
        pk[3] = cvtpk(b[2], b[3]);
        *(u32x4*)((char*)lds + row * 128 + ((c8 * 2) ^ ((row & 7) << 4))) = pk;
    }
}

// ---------------- prep kernels ----------------

// Per-(b, q/128, kv/64) nonzero flags from the f32 mask (zero mask => 0 atomics)
__global__ __launch_bounds__(256) void mask_flags(const float* __restrict__ m,
                                                  unsigned* __restrict__ flags) {
    int i = blockIdx.x * 256 + threadIdx.x;    // over B*S*S/4 = 2,097,152
    f32x4 v = ((const f32x4*)m)[i];
    bool nz = (v[0] != 0.f) | (v[1] != 0.f) | (v[2] != 0.f) | (v[3] != 0.f);
    if (nz) {
        size_t i4 = (size_t)i * 4;
        int b = (int)(i4 >> 22);
        int rem = (int)(i4 & 4194303);
        int qq = rem >> 11, kv = rem & 2047;
        atomicOr(flags + (b * 16 + (qq >> 7)) * 32 + (kv >> 6), 1u);
    }
}

// z<3: Wq/Wk/Wv [H][D][HD] -> w3[z][n][k]; z==3: Wo [K][N] -> wo[n][k]
__global__ __launch_bounds__(256) void pack_w4(const float* __restrict__ Wq,
                                               const float* __restrict__ Wk,
                                               const float* __restrict__ Wv,
                                               const float* __restrict__ Wo,
                                               __bf16* __restrict__ w3,
                                               __bf16* __restrict__ wo) {
    __shared__ __bf16 T[64][72];
    int tid = threadIdx.x;
    int z = blockIdx.z;
    int k0 = blockIdx.x * 64;
    if (z < 3) {
        int h = blockIdx.y;
        const float* W = z == 0 ? Wq : (z == 1 ? Wk : Wv);
#pragma unroll
        for (int it = 0; it < 4; ++it) {
            int idx = it * 1024 + tid * 4;
            int r = idx >> 6, e = idx & 63;
            f32x4 val = *(const f32x4*)(W + ((size_t)h * 1024 + k0 + r) * 64 + e);
#pragma unroll
            for (int j = 0; j < 4; ++j) T[r][e + j] = (__bf16)val[j];
        }
        __syncthreads();
        int e2 = tid >> 2, kc = (tid & 3) * 16;
        bf16x8 o0, o1;
#pragma unroll
        for (int i = 0; i < 8; ++i) { o0[i] = T[kc + i][e2]; o1[i] = T[kc + 8 + i][e2]; }
        __bf16* dst = w3 + ((size_t)z << 20) + (size_t)(h * 64 + e2) * 1024 + k0 + kc;
        *(bf16x8*)dst = o0;
        *(bf16x8*)(dst + 8) = o1;
    } else {
        int n0 = blockIdx.y * 64;
#pragma unroll
        for (int it = 0; it < 4; ++it) {
            int idx = it * 1024 + tid * 4;
            int r = idx >> 6, e = idx & 63;
            f32x4 val = *(const f32x4*)(Wo + (size_t)(k0 + r) * 1024 + n0 + e);
#pragma unroll
            for (int j = 0; j < 4; ++j) T[r][e + j] = (__bf16)val[j];
        }
        __syncthreads();
        int e2 = tid >> 2, kc = (tid & 3) * 16;
        bf16x8 o0, o1;
#pragma unroll
        for (int i = 0; i < 8; ++i) { o0[i] = T[kc + i][e2]; o1[i] = T[kc + 8 + i][e2]; }
        __bf16* dst = wo + (size_t)(n0 + e2) * 1024 + k0 + kc;
        *(bf16x8*)dst = o0;
        *(bf16x8*)(dst + 8) = o1;
    }
}

// ---------------- fused QKV GEMM: f32 A staging + fragment-pack epilogue ----
// grid (x=m 32, y=n 8, z=3; XCD = m%8). A read DIRECTLY from f32 q/k/v.
// z=0/1: write Q/K packed per (b,h): [s/32][kk][hi][q31][8]
// z=2:   write V packed per (b,h): [s/64][mt][kk][hi][e31][8] (bf16x4 stores)
__global__ __launch_bounds__(256) void gemm_qkv(
    const float* __restrict__ qf32, const float* __restrict__ kf32,
    const float* __restrict__ vf32, const __bf16* __restrict__ w3,
    const float* __restrict__ bq, const float* __restrict__ bk,
    const float* __restrict__ bv,
    __bf16* __restrict__ Qp, __bf16* __restrict__ Kp, __bf16* __restrict__ Vp) {
    __shared__ __bf16 As[128 * 64];
    __shared__ __bf16 Bs[128 * 64];
    int z = blockIdx.z;
    const float* A = z == 0 ? qf32 : (z == 1 ? kf32 : vf32);
    const __bf16* Bt = w3 + ((size_t)z << 20);
    const float* bias = z == 0 ? bq : (z == 1 ? bk : bv);
    float sc = z == 0 ? QSCL : 1.0f;

    int tid = threadIdx.x;
    int w = tid >> 6, lane = tid & 63, lg = lane >> 4, lr = lane & 15;
    int wr = (w >> 1) * 64, wc = (w & 1) * 64;
    int m0 = blockIdx.x * 128, n0 = blockIdx.y * 128;   // m fastest -> XCD=m%8
    f32x4 acc[4][4] = {};
    for (int k0 = 0; k0 < 1024; k0 += 64) {
        __syncthreads();
        stage_a_f32(A + (size_t)m0 * 1024 + k0, As, tid);
        stage_tile<128>(Bt + (size_t)n0 * 1024 + k0, 1024, Bs, tid);
        __syncthreads();
#pragma unroll
        for (int kk = 0; kk < 2; ++kk) {
            bf16x8 af[4], bfr[4];
#pragma unroll
            for (int t = 0; t < 4; ++t) {
                af[t] = lds_frag(As, wr + t * 16 + lr, lg * 16 + kk * 64);
                bfr[t] = lds_frag(Bs, wc + t * 16 + lr, lg * 16 + kk * 64);
            }
#pragma unroll
            for (int i = 0; i < 4; ++i)
#pragma unroll
                for (int j = 0; j < 4; ++j)
                    acc[i][j] = __builtin_amdgcn_mfma_f32_16x16x32_bf16(
                        af[i], bfr[j], acc[i][j], 0, 0, 0);
        }
    }
#pragma unroll
    for (int i = 0; i < 4; ++i) {
        int mb = m0 + wr + i * 16 + lg * 4;
        int b = mb >> 11, s = mb & 2047;
#pragma unroll
        for (int j = 0; j < 4; ++j) {
            int n = n0 + wc + j * 16 + lr;
            float bvv = bias[n];
            int h = n >> 6, e = n & 63;
            int bh = b * 16 + h;
            if (z == 2) {
                // packed V: contiguous over s&7 -> one bf16x4 store
                size_t addr = ((size_t)bh * 32 + (s >> 6)) * 4096 + (e >> 5) * 2048 +
                              ((s >> 4) & 3) * 512 + ((s >> 3) & 1) * 256 +
                              (e & 31) * 8 + (s & 7);
                bf16x4 o;
#pragma unroll
                for (int r = 0; r < 4; ++r) o[r] = (__bf16)(acc[i][j][r] + bvv);
                *(bf16x4*)(Vp + addr) = o;
            } else {
                __bf16* out = z == 0 ? Qp : Kp;
                size_t base = ((size_t)bh * 64 + (s >> 5)) * 2048 + (e >> 4) * 512 +
                              ((e >> 3) & 1) * 256 + (s & 31) * 8 + (e & 7);
#pragma unroll
                for (int r = 0; r < 4; ++r)
                    out[base + r * 8] = (__bf16)((acc[i][j][r] + bvv) * sc);
            }
        }
    }
}

// ---------------- final GEMM + GELU (grid: x=m 64, y=n 8; XCD = m%8) --------
__global__ __launch_bounds__(256) void gemm_out(const __bf16* __restrict__ A,
                                                const __bf16* __restrict__ Bt,
                                                const float* __restrict__ bias,
                                                float* __restrict__ dst) {
    __shared__ __bf16 As[64 * 64];
    __shared__ __bf16 Bs[128 * 64];
    int tid = threadIdx.x;
    int w = tid >> 6, lane = tid & 63, lg = lane >> 4, lr = lane & 15;
    int wr = (w >> 1) * 32, wc = (w & 1) * 64;
    int m0 = blockIdx.x * 64, n0 = blockIdx.y * 128;    // m fastest -> XCD=m%8
    f32x4 acc[2][4] = {};
    for (int k0 = 0; k0 < 1024; k0 += 64) {
        __syncthreads();
        stage_tile<64>(A + (size_t)m0 * 1024 + k0, 1024, As, tid);
        stage_tile<128>(Bt + (size_t)n0 * 1024 + k0, 1024, Bs, tid);
        __syncthreads();
#pragma unroll
        for (int kk = 0; kk < 2; ++kk) {
            bf16x8 af[2], bfr[4];
#pragma unroll
            for (int t = 0; t < 2; ++t)
                af[t] = lds_frag(As, wr + t * 16 + lr, lg * 16 + kk * 64);
#pragma unroll
            for (int t = 0; t < 4; ++t)
                bfr[t] = lds_frag(Bs, wc + t * 16 + lr, lg * 16 + kk * 64);
#pragma unroll
            for (int i = 0; i < 2; ++i)
#pragma unroll
                for (int j = 0; j < 4; ++j)
                    acc[i][j] = __builtin_amdgcn_mfma_f32_16x16x32_bf16(
                        af[i], bfr[j], acc[i][j], 0, 0, 0);
        }
    }
#pragma unroll
    for (int i = 0; i < 2; ++i) {
        int mb = m0 + wr + i * 16 + lg * 4;
#pragma unroll
        for (int j = 0; j < 4; ++j) {
            int n = n0 + wc + j * 16 + lr;
            float bvv = bias[n];
#pragma unroll
            for (int r = 0; r < 4; ++r) {
                float v = acc[i][j][r] + bvv;
                float g = v / (1.f + exp2f(GELC * v));
                dst[(size_t)(mb + r) * 1024 + n] = g;
            }
        }
    }
}

// ---------------- flash attention: LDS-free, fragment-packed streams --------
// 1D grid 1024, XCD decode as R9/R10. No barriers, no LDS. K reg-prefetched
// one tile ahead; V loads issued before exp2 block.
__global__ __launch_bounds__(256) void attn_kernel(
    const __bf16* __restrict__ Qp, const __bf16* __restrict__ Kp,
    const __bf16* __restrict__ Vp, const float* __restrict__ mask,
    const unsigned* __restrict__ flags,
    __bf16* __restrict__ Op0, __bf16* __restrict__ Op1,
    float* __restrict__ lacc) {
    int tid = threadIdx.x;
    int w = tid >> 6, l = tid & 63;
    int q31 = l & 31, hi = l >> 5;
    int i = blockIdx.x;
    int xcd = i & 7, j = i >> 3;
    int group = (j >> 4) * 8 + xcd;
    int qt = j & 15;
    int bh = group & 31, z = group >> 5;
    int b = bh >> 4, h = bh & 15;
    int qw = qt * 128 + w * 32;

    // Q frags: per (b,h) block sb = qw/32; lane offset kk*512 + l*8
    const __bf16* Qb = Qp + ((size_t)bh * 64 + (qw >> 5)) * 2048 + l * 8;
    bf16x8 qf[4];
#pragma unroll
    for (int kk = 0; kk < 4; ++kk) qf[kk] = *(const bf16x8*)(Qb + kk * 512);

    const __bf16* Kb = Kp + ((size_t)bh * 64 + z * 32) * 2048 + l * 8;
    const __bf16* Vb = Vp + ((size_t)bh * 32 + z * 16) * 4096 + l * 8;
    const float* mrow = mask + (size_t)b * 4194304 + (size_t)(qw + q31) * 2048 + (z << 10) + hi * 4;
    const unsigned* flg = flags + (b * 16 + qt) * 32 + z * 16;

    f32x16 O[2] = {};
    float la0 = 0.f, la1 = 0.f;

    // K prefetch tile 0: sb = kt*2 + mt, frag at sb*2048 + kk*512
    bf16x8 kf[2][4];
#pragma unroll
    for (int mt = 0; mt < 2; ++mt)
#pragma unroll
        for (int kk = 0; kk < 4; ++kk)
            kf[mt][kk] = *(const bf16x8*)(Kb + (mt * 4 + kk) * 512);

    for (int kt = 0; kt < 16; ++kt) {
        f32x16 T[2] = {};
        __builtin_amdgcn_s_setprio(1);
#pragma unroll
        for (int kk = 0; kk < 4; ++kk)
#pragma unroll
            for (int mt = 0; mt < 2; ++mt)
                T[mt] = __builtin_amdgcn_mfma_f32_32x32x16_bf16(kf[mt][kk], qf[kk], T[mt], 0, 0, 0);
        __builtin_amdgcn_s_setprio(0);

        // V loads for this tile + K prefetch for next: in flight across exp2
        bf16x8 vf[2][4];
#pragma unroll
        for (int mt = 0; mt < 2; ++mt)
#pragma unroll
            for (int kk = 0; kk < 4; ++kk)
                vf[mt][kk] = *(const bf16x8*)(Vb + (size_t)kt * 4096 + (mt * 4 + kk) * 512);
        if (kt < 15) {
#pragma unroll
            for (int mt = 0; mt < 2; ++mt)
#pragma unroll
                for (int kk = 0; kk < 4; ++kk)
                    kf[mt][kk] = *(const bf16x8*)(Kb + ((size_t)(kt + 1) * 2 + mt) * 2048 + kk * 512);
        }

        // flag-gated mask add (wave-uniform branch), then max-free exp2
        unsigned fl = __builtin_amdgcn_readfirstlane(flg[kt]);
        if (fl) {
#pragma unroll
            for (int mt = 0; mt < 2; ++mt)
#pragma unroll
                for (int g = 0; g < 4; ++g) {
                    f32x4 mk = *(const f32x4*)(mrow + kt * 64 + mt * 32 + g * 8);
#pragma unroll
                    for (int c = 0; c < 4; ++c)
                        T[mt][4 * g + c] = fmaf(mk[c], L2E, T[mt][4 * g + c]);
                }
        }
#pragma unroll
        for (int g = 0; g < 4; ++g) {
            float a0 = exp2f(T[0][4 * g + 0]);
            float a1 = exp2f(T[0][4 * g + 1]);
            float a2 = exp2f(T[0][4 * g + 2]);
            float a3 = exp2f(T[0][4 * g + 3]);
            float b0 = exp2f(T[1][4 * g + 0]);
            float b1 = exp2f(T[1][4 * g + 1]);
            float b2 = exp2f(T[1][4 * g + 2]);
            float b3 = exp2f(T[1][4 * g + 3]);
            la0 += (a0 + a1) + (a2 + a3);
            la1 += (b0 + b1) + (b2 + b3);
            T[0][4 * g + 0] = a0; T[0][4 * g + 1] = a1;
            T[0][4 * g + 2] = a2; T[0][4 * g + 3] = a3;
            T[1][4 * g + 0] = b0; T[1][4 * g + 1] = b1;
            T[1][4 * g + 2] = b2; T[1][4 * g + 3] = b3;
        }

        // P frags in-register: pf[kk][j] = P[q=q31][kv = kk*16 + hi*8 + j]
        bf16x8 pf[4];
#pragma unroll
        for (int kk = 0; kk < 4; ++kk) {
            int mt = kk >> 1;
            int gA = (2 * kk) & 3, gB = gA + 1;
            unsigned x0 = cvtpk(T[mt][4 * gA + 0], T[mt][4 * gA + 1]);
            unsigned x1 = cvtpk(T[mt][4 * gA + 2], T[mt][4 * gA + 3]);
            unsigned y0 = cvtpk(T[mt][4 * gB + 0], T[mt][4 * gB + 1]);
            unsigned y1 = cvtpk(T[mt][4 * gB + 2], T[mt][4 * gB + 3]);
            pswap(x0, y0);
            pswap(x1, y1);
            u32x4 packed; packed[0] = x0; packed[1] = x1; packed[2] = y0; packed[3] = y1;
            pf[kk] = __builtin_bit_cast(bf16x8, packed);
        }

        __builtin_amdgcn_s_setprio(1);
#pragma unroll
        for (int kk = 0; kk < 4; ++kk)
#pragma unroll
            for (int mt = 0; mt < 2; ++mt)
                O[mt] = __builtin_amdgcn_mfma_f32_32x32x16_bf16(vf[mt][kk], pf[kk], O[mt], 0, 0, 0);
        __builtin_amdgcn_s_setprio(0);
    }

    // combine via plain coalesced stores (one writer per address)
    float l_acc = la0 + la1;
    l_acc += __shfl_xor(l_acc, 32, 64);
    if (hi == 0)
        lacc[((size_t)z * 32 + b * 16 + h) * 2048 + qw + q31] = l_acc;
    __bf16* Ob = (z ? Op1 : Op0) + (((size_t)(b * 16 + h)) * 2048 + qw + q31) * 64 + hi * 4;
#pragma unroll
    for (int mt = 0; mt < 2; ++mt)
#pragma unroll
        for (int g = 0; g < 4; ++g) {
            bf16x4 o;
#pragma unroll
            for (int c = 0; c < 4; ++c) o[c] = (__bf16)O[mt][4 * g + c];
            *(bf16x4*)(Ob + mt * 32 + g * 8) = o;
        }
}

// normalize: x[b,s,h*64+e] = bf16((Op0+Op1)[b][h][s][e] / (l0+l1)[b][h][s])
__global__ __launch_bounds__(256) void attn_norm(const __bf16* __restrict__ Op0,
                                                 const __bf16* __restrict__ Op1,
                                                 const float* __restrict__ lacc,
                                                 __bf16* __restrict__ x) {
    int idx = blockIdx.x * 256 + threadIdx.x;   // 1,048,576 total
    int b = idx >> 19;
    int rem = idx & 524287;                     // h[4] s[11] e4[4]
    int h = rem >> 15;
    int s = (rem >> 4) & 2047;
    int e0 = (rem & 15) * 4;
    size_t base = (((size_t)(b * 16 + h)) * 2048 + s) * 64 + e0;
    bf16x4 a = *(const bf16x4*)(Op0 + base);
    bf16x4 c = *(const bf16x4*)(Op1 + base);
    size_t li = ((size_t)(b * 16 + h)) * 2048 + s;
    float inv = 1.0f / (lacc[li] + lacc[65536 + li]);
    bf16x4 r;
#pragma unroll
    for (int j = 0; j < 4; ++j)
        r[j] = (__bf16)(((float)a[j] + (float)c[j]) * inv);
    *(bf16x4*)(x + ((size_t)b * 2048 + s) * 1024 + h * 64 + e0) = r;
}

// ---------------- launch ----------------

extern "C" void kernel_launch(void* const* d_in, const int* in_sizes, int n_in,
                              void* d_out, int out_size, void* d_ws, size_t ws_size,
                              hipStream_t stream) {
    const float* q    = (const float*)d_in[0];
    const float* k    = (const float*)d_in[1];
    const float* v    = (const float*)d_in[2];
    const float* mask = (const float*)d_in[3];
    const float* Wq   = (const float*)d_in[4];
    const float* bq   = (const float*)d_in[5];
    const float* Wk   = (const float*)d_in[6];
    const float* bk   = (const float*)d_in[7];
    const float* Wv   = (const float*)d_in[8];
    const float* bv   = (const float*)d_in[9];
    const float* Wo   = (const float*)d_in[10];
    const float* bo   = (const float*)d_in[11];

    char* ws = (char*)d_ws;
    __bf16* Op0 = (__bf16*)(ws + (0ull  << 20));
    __bf16* Op1 = (__bf16*)(ws + (8ull  << 20));
    __bf16* xp  = (__bf16*)(ws + (16ull << 20));
    __bf16* w3  = (__bf16*)(ws + (24ull << 20));   // 6 MB
    __bf16* wo  = (__bf16*)(ws + (30ull << 20));   // 2 MB
    __bf16* Qpk = (__bf16*)(ws + (32ull << 20));   // packed Q
    __bf16* Kpk = (__bf16*)(ws + (40ull << 20));   // packed K
    __bf16* Vpk = (__bf16*)(ws + (48ull << 20));   // packed V
    float*  laccp = (float*)(ws + (56ull << 20));                        // 512 KB
    unsigned* flagp = (unsigned*)(ws + (56ull << 20) + (512ull << 10));  // 4 KB

    pack_w4<<<dim3(16, 16, 4), 256, 0, stream>>>(Wq, Wk, Wv, Wo, w3, wo);
    hipMemsetAsync(flagp, 0, 4096, stream);
    mask_flags<<<8192, 256, 0, stream>>>(mask, flagp);

    gemm_qkv<<<dim3(32, 8, 3), 256, 0, stream>>>(q, k, v, w3, bq, bk, bv,
                                                 Qpk, Kpk, Vpk);

    attn_kernel<<<dim3(1024), 256, 0, stream>>>(Qpk, Kpk, Vpk, mask, flagp,
                                                Op0, Op1, laccp);
    attn_norm<<<4096, 256, 0, stream>>>(Op0, Op1, laccp, xp);

    gemm_out<<<dim3(64, 8), 256, 0, stream>>>(xp, wo, bo, (float*)d_out);
}

// Round 13
// 158.086 us; speedup vs baseline: 1.0211x; 1.0211x over previous
//
#include <hip/hip_runtime.h>
#include <stdint.h>

// MultiHeadedAttention: B=2,S=2048,D=1024,H=16,HD=64
// R13: gemm_qkv/cvt3 reverted to R11 (R12's f32-A fusion serialized staging).
// attn: packed-fragment LDS staging -- K/V tiles are CONTIGUOUS 8KB in the
// packed stream, so global_load_lds is linear (no swizzle) and fragment
// ds_reads are lane-consecutive 16B (conflict-free). 4 waves/block share K/V
// (L2 traffic 1GB -> 256MB). Dbuf, 1 barrier/tile. In-reg P softmax, z=2
// kv-split, XCD swizzle, cheap bf16-partial combine all kept from R11.
// Workspace (MB): 0-8 qb->Op0, 8-16 kb->Op1, 16-24 vb->x, 24-30 w3, 30-32 wo,
// 32-40 Qp, 40-48 Kp, 48-56 Vp, 56+ lacc(512KB)+flags(4KB)

typedef __bf16 bf16x8 __attribute__((ext_vector_type(8)));
typedef __bf16 bf16x4 __attribute__((ext_vector_type(4)));
typedef float f32x4 __attribute__((ext_vector_type(4)));
typedef float f32x16 __attribute__((ext_vector_type(16)));
typedef unsigned u32x4 __attribute__((ext_vector_type(4)));

static constexpr float L2E  = 1.4426950408889634f;
static constexpr float QSCL = 0.18033688011112042f;   // 0.125 * log2(e)
static constexpr float GELC = -2.4554669595930157f;   // -1.702 * log2(e)

__device__ __forceinline__ void async_load16(const void* g, void* l) {
    __builtin_amdgcn_global_load_lds(
        (const __attribute__((address_space(1))) unsigned int*)(uintptr_t)g,
        (__attribute__((address_space(3))) unsigned int*)(unsigned int)(uintptr_t)l,
        16, 0, 0);
}

// Stage ROWS x 64-bf16 tile into LDS, phys = row*128 + (kb ^ ((row&7)<<4)).
template <int ROWS>
__device__ __forceinline__ void stage_tile(const __bf16* g, int ld, __bf16* lds, int tid) {
#pragma unroll
    for (int r = 0; r < ROWS / 32; ++r) {
        int p = r * 4096 + tid * 16;
        int row = p >> 7;
        int kbp = p & 127;
        int kbl = kbp ^ ((row & 7) << 4);
        async_load16((const char*)(g + (size_t)row * ld) + kbl,
                     (char*)lds + (p & ~1023));
    }
}

__device__ __forceinline__ bf16x8 lds_frag(const __bf16* base, int row, int kb) {
    return *(const bf16x8*)((const char*)base + (row << 7) + (kb ^ ((row & 7) << 4)));
}

__device__ __forceinline__ unsigned cvtpk(float a, float b) {
    unsigned d;
    asm("v_cvt_pk_bf16_f32 %0, %1, %2" : "=v"(d) : "v"(a), "v"(b));
    return d;
}
__device__ __forceinline__ void pswap(unsigned& a, unsigned& b) {
    asm("v_permlane32_swap_b32 %0, %1" : "+v"(a), "+v"(b));
}

// ---------------- prep kernels ----------------

__global__ __launch_bounds__(256) void cvt3_kernel(const float* __restrict__ q,
                                                   const float* __restrict__ k,
                                                   const float* __restrict__ v,
                                                   __bf16* __restrict__ qb,
                                                   __bf16* __restrict__ kb,
                                                   __bf16* __restrict__ vb) {
    int z = blockIdx.y;
    const float* src = z == 0 ? q : (z == 1 ? k : v);
    __bf16* dst = z == 0 ? qb : (z == 1 ? kb : vb);
    int i = blockIdx.x * 256 + threadIdx.x;
    f32x4 val = ((const f32x4*)src)[i];
    bf16x4 o;
    o[0] = (__bf16)val[0]; o[1] = (__bf16)val[1];
    o[2] = (__bf16)val[2]; o[3] = (__bf16)val[3];
    ((bf16x4*)dst)[i] = o;
}

// Per-(b, q/128, kv/64) nonzero flags from the f32 mask (zero mask => 0 atomics)
__global__ __launch_bounds__(256) void mask_flags(const float* __restrict__ m,
                                                  unsigned* __restrict__ flags) {
    int i = blockIdx.x * 256 + threadIdx.x;    // over B*S*S/4 = 2,097,152
    f32x4 v = ((const f32x4*)m)[i];
    bool nz = (v[0] != 0.f) | (v[1] != 0.f) | (v[2] != 0.f) | (v[3] != 0.f);
    if (nz) {
        size_t i4 = (size_t)i * 4;
        int b = (int)(i4 >> 22);
        int rem = (int)(i4 & 4194303);
        int qq = rem >> 11, kv = rem & 2047;
        atomicOr(flags + (b * 16 + (qq >> 7)) * 32 + (kv >> 6), 1u);
    }
}

// z<3: Wq/Wk/Wv [H][D][HD] -> w3[z][n][k]; z==3: Wo [K][N] -> wo[n][k]
__global__ __launch_bounds__(256) void pack_w4(const float* __restrict__ Wq,
                                               const float* __restrict__ Wk,
                                               const float* __restrict__ Wv,
                                               const float* __restrict__ Wo,
                                               __bf16* __restrict__ w3,
                                               __bf16* __restrict__ wo) {
    __shared__ __bf16 T[64][72];
    int tid = threadIdx.x;
    int z = blockIdx.z;
    int k0 = blockIdx.x * 64;
    if (z < 3) {
        int h = blockIdx.y;
        const float* W = z == 0 ? Wq : (z == 1 ? Wk : Wv);
#pragma unroll
        for (int it = 0; it < 4; ++it) {
            int idx = it * 1024 + tid * 4;
            int r = idx >> 6, e = idx & 63;
            f32x4 val = *(const f32x4*)(W + ((size_t)h * 1024 + k0 + r) * 64 + e);
#pragma unroll
            for (int j = 0; j < 4; ++j) T[r][e + j] = (__bf16)val[j];
        }
        __syncthreads();
        int e2 = tid >> 2, kc = (tid & 3) * 16;
        bf16x8 o0, o1;
#pragma unroll
        for (int i = 0; i < 8; ++i) { o0[i] = T[kc + i][e2]; o1[i] = T[kc + 8 + i][e2]; }
        __bf16* dst = w3 + ((size_t)z << 20) + (size_t)(h * 64 + e2) * 1024 + k0 + kc;
        *(bf16x8*)dst = o0;
        *(bf16x8*)(dst + 8) = o1;
    } else {
        int n0 = blockIdx.y * 64;
#pragma unroll
        for (int it = 0; it < 4; ++it) {
            int idx = it * 1024 + tid * 4;
            int r = idx >> 6, e = idx & 63;
            f32x4 val = *(const f32x4*)(Wo + (size_t)(k0 + r) * 1024 + n0 + e);
#pragma unroll
            for (int j = 0; j < 4; ++j) T[r][e + j] = (__bf16)val[j];
        }
        __syncthreads();
        int e2 = tid >> 2, kc = (tid & 3) * 16;
        bf16x8 o0, o1;
#pragma unroll
        for (int i = 0; i < 8; ++i) { o0[i] = T[kc + i][e2]; o1[i] = T[kc + 8 + i][e2]; }
        __bf16* dst = wo + (size_t)(n0 + e2) * 1024 + k0 + kc;
        *(bf16x8*)dst = o0;
        *(bf16x8*)(dst + 8) = o1;
    }
}

// ---------------- fused QKV GEMM + fragment-pack epilogue (R11) -------------
// grid (x=m 32, y=n 8, z=3; XCD = m%8).
__global__ __launch_bounds__(256) void gemm_qkv(
    const __bf16* __restrict__ qb, const __bf16* __restrict__ kb,
    const __bf16* __restrict__ vb, const __bf16* __restrict__ w3,
    const float* __restrict__ bq, const float* __restrict__ bk,
    const float* __restrict__ bv,
    __bf16* __restrict__ Qp, __bf16* __restrict__ Kp, __bf16* __restrict__ Vp) {
    __shared__ __bf16 As[128 * 64];
    __shared__ __bf16 Bs[128 * 64];
    int z = blockIdx.z;
    const __bf16* A = z == 0 ? qb : (z == 1 ? kb : vb);
    const __bf16* Bt = w3 + ((size_t)z << 20);
    const float* bias = z == 0 ? bq : (z == 1 ? bk : bv);
    float sc = z == 0 ? QSCL : 1.0f;

    int tid = threadIdx.x;
    int w = tid >> 6, lane = tid & 63, lg = lane >> 4, lr = lane & 15;
    int wr = (w >> 1) * 64, wc = (w & 1) * 64;
    int m0 = blockIdx.x * 128, n0 = blockIdx.y * 128;   // m fastest -> XCD=m%8
    f32x4 acc[4][4] = {};
    for (int k0 = 0; k0 < 1024; k0 += 64) {
        __syncthreads();
        stage_tile<128>(A + (size_t)m0 * 1024 + k0, 1024, As, tid);
        stage_tile<128>(Bt + (size_t)n0 * 1024 + k0, 1024, Bs, tid);
        __syncthreads();
#pragma unroll
        for (int kk = 0; kk < 2; ++kk) {
            bf16x8 af[4], bfr[4];
#pragma unroll
            for (int t = 0; t < 4; ++t) {
                af[t] = lds_frag(As, wr + t * 16 + lr, lg * 16 + kk * 64);
                bfr[t] = lds_frag(Bs, wc + t * 16 + lr, lg * 16 + kk * 64);
            }
#pragma unroll
            for (int i = 0; i < 4; ++i)
#pragma unroll
                for (int j = 0; j < 4; ++j)
                    acc[i][j] = __builtin_amdgcn_mfma_f32_16x16x32_bf16(
                        af[i], bfr[j], acc[i][j], 0, 0, 0);
        }
    }
#pragma unroll
    for (int i = 0; i < 4; ++i) {
        int mb = m0 + wr + i * 16 + lg * 4;
        int b = mb >> 11, s = mb & 2047;
#pragma unroll
        for (int j = 0; j < 4; ++j) {
            int n = n0 + wc + j * 16 + lr;
            float bvv = bias[n];
            int h = n >> 6, e = n & 63;
            int bh = b * 16 + h;
            if (z == 2) {
                size_t addr = ((size_t)bh * 32 + (s >> 6)) * 4096 + (e >> 5) * 2048 +
                              ((s >> 4) & 3) * 512 + ((s >> 3) & 1) * 256 +
                              (e & 31) * 8 + (s & 7);
                bf16x4 o;
#pragma unroll
                for (int r = 0; r < 4; ++r) o[r] = (__bf16)(acc[i][j][r] + bvv);
                *(bf16x4*)(Vp + addr) = o;
            } else {
                __bf16* out = z == 0 ? Qp : Kp;
                size_t base = ((size_t)bh * 64 + (s >> 5)) * 2048 + (e >> 4) * 512 +
                              ((e >> 3) & 1) * 256 + (s & 31) * 8 + (e & 7);
#pragma unroll
                for (int r = 0; r < 4; ++r)
                    out[base + r * 8] = (__bf16)((acc[i][j][r] + bvv) * sc);
            }
        }
    }
}

// ---------------- final GEMM + GELU (grid: x=m 64, y=n 8; XCD = m%8) --------
__global__ __launch_bounds__(256) void gemm_out(const __bf16* __restrict__ A,
                                                const __bf16* __restrict__ Bt,
                                                const float* __restrict__ bias,
                                                float* __restrict__ dst) {
    __shared__ __bf16 As[64 * 64];
    __shared__ __bf16 Bs[128 * 64];
    int tid = threadIdx.x;
    int w = tid >> 6, lane = tid & 63, lg = lane >> 4, lr = lane & 15;
    int wr = (w >> 1) * 32, wc = (w & 1) * 64;
    int m0 = blockIdx.x * 64, n0 = blockIdx.y * 128;    // m fastest -> XCD=m%8
    f32x4 acc[2][4] = {};
    for (int k0 = 0; k0 < 1024; k0 += 64) {
        __syncthreads();
        stage_tile<64>(A + (size_t)m0 * 1024 + k0, 1024, As, tid);
        stage_tile<128>(Bt + (size_t)n0 * 1024 + k0, 1024, Bs, tid);
        __syncthreads();
#pragma unroll
        for (int kk = 0; kk < 2; ++kk) {
            bf16x8 af[2], bfr[4];
#pragma unroll
            for (int t = 0; t < 2; ++t)
                af[t] = lds_frag(As, wr + t * 16 + lr, lg * 16 + kk * 64);
#pragma unroll
            for (int t = 0; t < 4; ++t)
                bfr[t] = lds_frag(Bs, wc + t * 16 + lr, lg * 16 + kk * 64);
#pragma unroll
            for (int i = 0; i < 2; ++i)
#pragma unroll
                for (int j = 0; j < 4; ++j)
                    acc[i][j] = __builtin_amdgcn_mfma_f32_16x16x32_bf16(
                        af[i], bfr[j], acc[i][j], 0, 0, 0);
        }
    }
#pragma unroll
    for (int i = 0; i < 2; ++i) {
        int mb = m0 + wr + i * 16 + lg * 4;
#pragma unroll
        for (int j = 0; j < 4; ++j) {
            int n = n0 + wc + j * 16 + lr;
            float bvv = bias[n];
#pragma unroll
            for (int r = 0; r < 4; ++r) {
                float v = acc[i][j][r] + bvv;
                float g = v / (1.f + exp2f(GELC * v));
                dst[(size_t)(mb + r) * 1024 + n] = g;
            }
        }
    }
}

// ---------------- flash attention: packed-fragment LDS staging --------------
// 1D grid 1024, XCD decode as R9-R11. 4 waves share K/V tiles staged in LDS:
// packed stream is contiguous 8KB/tile -> linear global_load_lds (no swizzle),
// fragment ds_reads are lane-consecutive 16B (conflict-free). Dbuf, 1 barrier
// per tile. In-reg P softmax (cvt_pk+permlane), flag-gated f32 mask, max-free.
__global__ __launch_bounds__(256) void attn_kernel(
    const __bf16* __restrict__ Qp, const __bf16* __restrict__ Kp,
    const __bf16* __restrict__ Vp, const float* __restrict__ mask,
    const unsigned* __restrict__ flags,
    __bf16* __restrict__ Op0, __bf16* __restrict__ Op1,
    float* __restrict__ lacc) {
    __shared__ __bf16 Ks[2][4096];   // 8KB per buffer
    __shared__ __bf16 Vs[2][4096];
    int tid = threadIdx.x;
    int w = tid >> 6, l = tid & 63;
    int q31 = l & 31, hi = l >> 5;
    int i = blockIdx.x;
    int xcd = i & 7, j = i >> 3;
    int group = (j >> 4) * 8 + xcd;
    int qt = j & 15;
    int bh = group & 31, z = group >> 5;
    int b = bh >> 4, h = bh & 15;
    int qw = qt * 128 + w * 32;

    // Q frags: per (b,h) block sb = qw/32; lane offset kk*512 + l*8
    const __bf16* Qb = Qp + ((size_t)bh * 64 + (qw >> 5)) * 2048 + l * 8;
    bf16x8 qf[4];
#pragma unroll
    for (int kk = 0; kk < 4; ++kk) qf[kk] = *(const bf16x8*)(Qb + kk * 512);

    // packed K/V tile kt is 4096 elems (8KB) contiguous
    const __bf16* Kb = Kp + ((size_t)bh * 64 + z * 32) * 2048;
    const __bf16* Vb = Vp + ((size_t)bh * 32 + z * 16) * 4096;
    const float* mrow = mask + (size_t)b * 4194304 + (size_t)(qw + q31) * 2048 + (z << 10) + hi * 4;
    const unsigned* flg = flags + (b * 16 + qt) * 32 + z * 16;

    f32x16 O[2] = {};
    float la0 = 0.f, la1 = 0.f;

    // prologue: stage tile 0 into buf 0 (linear: dest base wave-uniform)
#pragma unroll
    for (int r = 0; r < 2; ++r) {
        int p = r * 4096 + tid * 16;
        async_load16((const char*)Kb + p, (char*)Ks[0] + (p & ~1023));
        async_load16((const char*)Vb + p, (char*)Vs[0] + (p & ~1023));
    }

    for (int kt = 0; kt < 16; ++kt) {
        int buf = kt & 1;
        __syncthreads();   // buf staged (barrier drains vmcnt); buf^1 free
        if (kt < 15) {
#pragma unroll
            for (int r = 0; r < 2; ++r) {
                int p = r * 4096 + tid * 16;
                async_load16((const char*)(Kb + (size_t)(kt + 1) * 4096) + p,
                             (char*)Ks[buf ^ 1] + (p & ~1023));
                async_load16((const char*)(Vb + (size_t)(kt + 1) * 4096) + p,
                             (char*)Vs[buf ^ 1] + (p & ~1023));
            }
        }
        f32x16 T[2] = {};
        __builtin_amdgcn_s_setprio(1);
#pragma unroll
        for (int kk = 0; kk < 4; ++kk)
#pragma unroll
            for (int mt = 0; mt < 2; ++mt) {
                bf16x8 a = *(const bf16x8*)(Ks[buf] + mt * 2048 + kk * 512 + l * 8);
                T[mt] = __builtin_amdgcn_mfma_f32_32x32x16_bf16(a, qf[kk], T[mt], 0, 0, 0);
            }
        __builtin_amdgcn_s_setprio(0);

        // flag-gated mask add (wave-uniform branch), then max-free exp2
        unsigned fl = __builtin_amdgcn_readfirstlane(flg[kt]);
        if (fl) {
#pragma unroll
            for (int mt = 0; mt < 2; ++mt)
#pragma unroll
                for (int g = 0; g < 4; ++g) {
                    f32x4 mk = *(const f32x4*)(mrow + kt * 64 + mt * 32 + g * 8);
#pragma unroll
                    for (int c = 0; c < 4; ++c)
                        T[mt][4 * g + c] = fmaf(mk[c], L2E, T[mt][4 * g + c]);
                }
        }
#pragma unroll
        for (int g = 0; g < 4; ++g) {
            float a0 = exp2f(T[0][4 * g + 0]);
            float a1 = exp2f(T[0][4 * g + 1]);
            float a2 = exp2f(T[0][4 * g + 2]);
            float a3 = exp2f(T[0][4 * g + 3]);
            float b0 = exp2f(T[1][4 * g + 0]);
            float b1 = exp2f(T[1][4 * g + 1]);
            float b2 = exp2f(T[1][4 * g + 2]);
            float b3 = exp2f(T[1][4 * g + 3]);
            la0 += (a0 + a1) + (a2 + a3);
            la1 += (b0 + b1) + (b2 + b3);
            T[0][4 * g + 0] = a0; T[0][4 * g + 1] = a1;
            T[0][4 * g + 2] = a2; T[0][4 * g + 3] = a3;
            T[1][4 * g + 0] = b0; T[1][4 * g + 1] = b1;
            T[1][4 * g + 2] = b2; T[1][4 * g + 3] = b3;
        }

        // P frags in-register: pf[kk][j] = P[q=q31][kv = kk*16 + hi*8 + j]
        bf16x8 pf[4];
#pragma unroll
        for (int kk = 0; kk < 4; ++kk) {
            int mt = kk >> 1;
            int gA = (2 * kk) & 3, gB = gA + 1;
            unsigned x0 = cvtpk(T[mt][4 * gA + 0], T[mt][4 * gA + 1]);
            unsigned x1 = cvtpk(T[mt][4 * gA + 2], T[mt][4 * gA + 3]);
            unsigned y0 = cvtpk(T[mt][4 * gB + 0], T[mt][4 * gB + 1]);
            unsigned y1 = cvtpk(T[mt][4 * gB + 2], T[mt][4 * gB + 3]);
            pswap(x0, y0);
            pswap(x1, y1);
            u32x4 packed; packed[0] = x0; packed[1] = x1; packed[2] = y0; packed[3] = y1;
            pf[kk] = __builtin_bit_cast(bf16x8, packed);
        }

        __builtin_amdgcn_s_setprio(1);
#pragma unroll
        for (int kk = 0; kk < 4; ++kk)
#pragma unroll
            for (int mt = 0; mt < 2; ++mt) {
                bf16x8 vv = *(const bf16x8*)(Vs[buf] + mt * 2048 + kk * 512 + l * 8);
                O[mt] = __builtin_amdgcn_mfma_f32_32x32x16_bf16(vv, pf[kk], O[mt], 0, 0, 0);
            }
        __builtin_amdgcn_s_setprio(0);
    }

    // combine via plain coalesced stores (one writer per address)
    float l_acc = la0 + la1;
    l_acc += __shfl_xor(l_acc, 32, 64);
    if (hi == 0)
        lacc[((size_t)z * 32 + b * 16 + h) * 2048 + qw + q31] = l_acc;
    __bf16* Ob = (z ? Op1 : Op0) + (((size_t)(b * 16 + h)) * 2048 + qw + q31) * 64 + hi * 4;
#pragma unroll
    for (int mt = 0; mt < 2; ++mt)
#pragma unroll
        for (int g = 0; g < 4; ++g) {
            bf16x4 o;
#pragma unroll
            for (int c = 0; c < 4; ++c) o[c] = (__bf16)O[mt][4 * g + c];
            *(bf16x4*)(Ob + mt * 32 + g * 8) = o;
        }
}

// normalize: x[b,s,h*64+e] = bf16((Op0+Op1)[b][h][s][e] / (l0+l1)[b][h][s])
__global__ __launch_bounds__(256) void attn_norm(const __bf16* __restrict__ Op0,
                                                 const __bf16* __restrict__ Op1,
                                                 const float* __restrict__ lacc,
                                                 __bf16* __restrict__ x) {
    int idx = blockIdx.x * 256 + threadIdx.x;   // 1,048,576 total
    int b = idx >> 19;
    int rem = idx & 524287;                     // h[4] s[11] e4[4]
    int h = rem >> 15;
    int s = (rem >> 4) & 2047;
    int e0 = (rem & 15) * 4;
    size_t base = (((size_t)(b * 16 + h)) * 2048 + s) * 64 + e0;
    bf16x4 a = *(const bf16x4*)(Op0 + base);
    bf16x4 c = *(const bf16x4*)(Op1 + base);
    size_t li = ((size_t)(b * 16 + h)) * 2048 + s;
    float inv = 1.0f / (lacc[li] + lacc[65536 + li]);
    bf16x4 r;
#pragma unroll
    for (int j = 0; j < 4; ++j)
        r[j] = (__bf16)(((float)a[j] + (float)c[j]) * inv);
    *(bf16x4*)(x + ((size_t)b * 2048 + s) * 1024 + h * 64 + e0) = r;
}

// ---------------- launch ----------------

extern "C" void kernel_launch(void* const* d_in, const int* in_sizes, int n_in,
                              void* d_out, int out_size, void* d_ws, size_t ws_size,
                              hipStream_t stream) {
    const float* q    = (const float*)d_in[0];
    const float* k    = (const float*)d_in[1];
    const float* v    = (const float*)d_in[2];
    const float* mask = (const float*)d_in[3];
    const float* Wq   = (const float*)d_in[4];
    const float* bq   = (const float*)d_in[5];
    const float* Wk   = (const float*)d_in[6];
    const float* bk   = (const float*)d_in[7];
    const float* Wv   = (const float*)d_in[8];
    const float* bv   = (const float*)d_in[9];
    const float* Wo   = (const float*)d_in[10];
    const float* bo   = (const float*)d_in[11];

    char* ws = (char*)d_ws;
    __bf16* qb  = (__bf16*)(ws + (0ull  << 20));   // -> Op0 after gemm_qkv
    __bf16* kb  = (__bf16*)(ws + (8ull  << 20));   // -> Op1 after gemm_qkv
    __bf16* vb  = (__bf16*)(ws + (16ull << 20));   // -> x   after gemm_qkv
    __bf16* w3  = (__bf16*)(ws + (24ull << 20));   // 6 MB
    __bf16* wo  = (__bf16*)(ws + (30ull << 20));   // 2 MB
    __bf16* Qpk = (__bf16*)(ws + (32ull << 20));   // packed Q
    __bf16* Kpk = (__bf16*)(ws + (40ull << 20));   // packed K
    __bf16* Vpk = (__bf16*)(ws + (48ull << 20));   // packed V
    float*  laccp = (float*)(ws + (56ull << 20));                        // 512 KB
    unsigned* flagp = (unsigned*)(ws + (56ull << 20) + (512ull << 10));  // 4 KB
    __bf16* Op0 = qb;
    __bf16* Op1 = kb;
    __bf16* xp  = vb;

    cvt3_kernel<<<dim3(4096, 3), 256, 0, stream>>>(q, k, v, qb, kb, vb);
    pack_w4<<<dim3(16, 16, 4), 256, 0, stream>>>(Wq, Wk, Wv, Wo, w3, wo);
    hipMemsetAsync(flagp, 0, 4096, stream);
    mask_flags<<<8192, 256, 0, stream>>>(mask, flagp);

    gemm_qkv<<<dim3(32, 8, 3), 256, 0, stream>>>(qb, kb, vb, w3, bq, bk, bv,
                                                 Qpk, Kpk, Vpk);

    attn_kernel<<<dim3(1024), 256, 0, stream>>>(Qpk, Kpk, Vpk, mask, flagp,
                                                Op0, Op1, laccp);
    attn_norm<<<4096, 256, 0, stream>>>(Op0, Op1, laccp, xp);

    gemm_out<<<dim3(64, 8), 256, 0, stream>>>(xp, wo, bo, (float*)d_out);
}

// Round 14
// 145.965 us; speedup vs baseline: 1.1059x; 1.0830x over previous
//
#include <hip/hip_runtime.h>
#include <stdint.h>

// MultiHeadedAttention: B=2,S=2048,D=1024,H=16,HD=64
// R14: (1) cvt3 DELETED -- gemm_qkv stages f32 A via global_load_lds DMA into
// a swizzled f32 LDS tile (R12's failure was reg-staging serialization; DMA
// keeps overlap) and converts to bf16 at fragment read (cvt_pk, bit-identical
// rounding). (2) attn (R11 LDS-free form) + gemm_out use raw v_exp_f32
// (__builtin_amdgcn_exp2f) -- exp2f's libm fixup was ~4x the VALU cost and
// attn is VALU-issue-bound (VALUBusy 60%).
// Workspace (MB): 0-8 Op0, 8-16 Op1, 16-24 x, 24-30 w3, 30-32 wo,
// 32-40 Qp, 40-48 Kp, 48-56 Vp, 56+ lacc(512KB)+flags(4KB)

typedef __bf16 bf16x8 __attribute__((ext_vector_type(8)));
typedef __bf16 bf16x4 __attribute__((ext_vector_type(4)));
typedef float f32x4 __attribute__((ext_vector_type(4)));
typedef float f32x16 __attribute__((ext_vector_type(16)));
typedef unsigned u32x4 __attribute__((ext_vector_type(4)));

static constexpr float L2E  = 1.4426950408889634f;
static constexpr float QSCL = 0.18033688011112042f;   // 0.125 * log2(e)
static constexpr float GELC = -2.4554669595930157f;   // -1.702 * log2(e)

#if __has_builtin(__builtin_amdgcn_exp2f)
__device__ __forceinline__ float fexp2(float x) { return __builtin_amdgcn_exp2f(x); }
#else
__device__ __forceinline__ float fexp2(float x) {
    float r; asm("v_exp_f32 %0, %1" : "=v"(r) : "v"(x)); return r;
}
#endif

__device__ __forceinline__ void async_load16(const void* g, void* l) {
    __builtin_amdgcn_global_load_lds(
        (const __attribute__((address_space(1))) unsigned int*)(uintptr_t)g,
        (__attribute__((address_space(3))) unsigned int*)(unsigned int)(uintptr_t)l,
        16, 0, 0);
}

// Stage ROWS x 64-bf16 tile into LDS, phys = row*128 + (kb ^ ((row&7)<<4)).
template <int ROWS>
__device__ __forceinline__ void stage_tile(const __bf16* g, int ld, __bf16* lds, int tid) {
#pragma unroll
    for (int r = 0; r < ROWS / 32; ++r) {
        int p = r * 4096 + tid * 16;
        int row = p >> 7;
        int kbp = p & 127;
        int kbl = kbp ^ ((row & 7) << 4);
        async_load16((const char*)(g + (size_t)row * ld) + kbl,
                     (char*)lds + (p & ~1023));
    }
}

// Stage 128x64 f32 tile (row stride ld f32) into LDS, 32B-XOR swizzle:
// phys = row*256 + (cb ^ ((row&7)<<5)); linear dest + inverse-swizzled source.
__device__ __forceinline__ void stage_a32(const float* g, float* lds, int tid) {
#pragma unroll
    for (int r = 0; r < 8; ++r) {
        int p = r * 4096 + tid * 16;     // byte offset in 32KB tile
        int row = p >> 8;                // 256B per row
        int cb  = p & 255;
        int cbs = cb ^ ((row & 7) << 5);
        async_load16((const char*)(g + (size_t)row * 1024) + cbs,
                     (char*)lds + (p & ~1023));
    }
}

__device__ __forceinline__ bf16x8 lds_frag(const __bf16* base, int row, int kb) {
    return *(const bf16x8*)((const char*)base + (row << 7) + (kb ^ ((row & 7) << 4)));
}

__device__ __forceinline__ unsigned cvtpk(float a, float b) {
    unsigned d;
    asm("v_cvt_pk_bf16_f32 %0, %1, %2" : "=v"(d) : "v"(a), "v"(b));
    return d;
}
__device__ __forceinline__ void pswap(unsigned& a, unsigned& b) {
    asm("v_permlane32_swap_b32 %0, %1" : "+v"(a), "+v"(b));
}

// f32 LDS tile -> bf16x8 fragment (8 elems at elem-offset eo of row), RNE.
__device__ __forceinline__ bf16x8 frag_f32(const float* base, int row, int eo) {
    int cb = (eo * 4) ^ ((row & 7) << 5);
    const char* p = (const char*)base + row * 256 + cb;
    f32x4 a = *(const f32x4*)p;
    f32x4 b = *(const f32x4*)(p + 16);
    u32x4 pk;
    pk[0] = cvtpk(a[0], a[1]); pk[1] = cvtpk(a[2], a[3]);
    pk[2] = cvtpk(b[0], b[1]); pk[3] = cvtpk(b[2], b[3]);
    return __builtin_bit_cast(bf16x8, pk);
}

// ---------------- prep kernels ----------------

// Per-(b, q/128, kv/64) nonzero flags from the f32 mask (zero mask => 0 atomics)
__global__ __launch_bounds__(256) void mask_flags(const float* __restrict__ m,
                                                  unsigned* __restrict__ flags) {
    int i = blockIdx.x * 256 + threadIdx.x;    // over B*S*S/4 = 2,097,152
    f32x4 v = ((const f32x4*)m)[i];
    bool nz = (v[0] != 0.f) | (v[1] != 0.f) | (v[2] != 0.f) | (v[3] != 0.f);
    if (nz) {
        size_t i4 = (size_t)i * 4;
        int b = (int)(i4 >> 22);
        int rem = (int)(i4 & 4194303);
        int qq = rem >> 11, kv = rem & 2047;
        atomicOr(flags + (b * 16 + (qq >> 7)) * 32 + (kv >> 6), 1u);
    }
}

// z<3: Wq/Wk/Wv [H][D][HD] -> w3[z][n][k]; z==3: Wo [K][N] -> wo[n][k]
__global__ __launch_bounds__(256) void pack_w4(const float* __restrict__ Wq,
                                               const float* __restrict__ Wk,
                                               const float* __restrict__ Wv,
                                               const float* __restrict__ Wo,
                                               __bf16* __restrict__ w3,
                                               __bf16* __restrict__ wo) {
    __shared__ __bf16 T[64][72];
    int tid = threadIdx.x;
    int z = blockIdx.z;
    int k0 = blockIdx.x * 64;
    if (z < 3) {
        int h = blockIdx.y;
        const float* W = z == 0 ? Wq : (z == 1 ? Wk : Wv);
#pragma unroll
        for (int it = 0; it < 4; ++it) {
            int idx = it * 1024 + tid * 4;
            int r = idx >> 6, e = idx & 63;
            f32x4 val = *(const f32x4*)(W + ((size_t)h * 1024 + k0 + r) * 64 + e);
#pragma unroll
            for (int j = 0; j < 4; ++j) T[r][e + j] = (__bf16)val[j];
        }
        __syncthreads();
        int e2 = tid >> 2, kc = (tid & 3) * 16;
        bf16x8 o0, o1;
#pragma unroll
        for (int i = 0; i < 8; ++i) { o0[i] = T[kc + i][e2]; o1[i] = T[kc + 8 + i][e2]; }
        __bf16* dst = w3 + ((size_t)z << 20) + (size_t)(h * 64 + e2) * 1024 + k0 + kc;
        *(bf16x8*)dst = o0;
        *(bf16x8*)(dst + 8) = o1;
    } else {
        int n0 = blockIdx.y * 64;
#pragma unroll
        for (int it = 0; it < 4; ++it) {
            int idx = it * 1024 + tid * 4;
            int r = idx >> 6, e = idx & 63;
            f32x4 val = *(const f32x4*)(Wo + (size_t)(k0 + r) * 1024 + n0 + e);
#pragma unroll
            for (int j = 0; j < 4; ++j) T[r][e + j] = (__bf16)val[j];
        }
        __syncthreads();
        int e2 = tid >> 2, kc = (tid & 3) * 16;
        bf16x8 o0, o1;
#pragma unroll
        for (int i = 0; i < 8; ++i) { o0[i] = T[kc + i][e2]; o1[i] = T[kc + 8 + i][e2]; }
        __bf16* dst = wo + (size_t)(n0 + e2) * 1024 + k0 + kc;
        *(bf16x8*)dst = o0;
        *(bf16x8*)(dst + 8) = o1;
    }
}

// ---------------- fused QKV GEMM: f32-A DMA staging + fragment-pack epilogue
// grid (x=m 32, y=n 8, z=3; XCD = m%8). A staged f32 via global_load_lds
// (swizzled source), converted to bf16 at frag read (cvt_pk = RNE).
__global__ __launch_bounds__(256) void gemm_qkv(
    const float* __restrict__ qf, const float* __restrict__ kf2,
    const float* __restrict__ vf2, const __bf16* __restrict__ w3,
    const float* __restrict__ bq, const float* __restrict__ bk,
    const float* __restrict__ bv,
    __bf16* __restrict__ Qp, __bf16* __restrict__ Kp, __bf16* __restrict__ Vp) {
    __shared__ float  Asf[128 * 64];   // 32 KB
    __shared__ __bf16 Bs[128 * 64];    // 16 KB
    int z = blockIdx.z;
    const float* A = z == 0 ? qf : (z == 1 ? kf2 : vf2);
    const __bf16* Bt = w3 + ((size_t)z << 20);
    const float* bias = z == 0 ? bq : (z == 1 ? bk : bv);
    float sc = z == 0 ? QSCL : 1.0f;

    int tid = threadIdx.x;
    int w = tid >> 6, lane = tid & 63, lg = lane >> 4, lr = lane & 15;
    int wr = (w >> 1) * 64, wc = (w & 1) * 64;
    int m0 = blockIdx.x * 128, n0 = blockIdx.y * 128;   // m fastest -> XCD=m%8
    f32x4 acc[4][4] = {};
    for (int k0 = 0; k0 < 1024; k0 += 64) {
        __syncthreads();
        stage_a32(A + (size_t)m0 * 1024 + k0, Asf, tid);
        stage_tile<128>(Bt + (size_t)n0 * 1024 + k0, 1024, Bs, tid);
        __syncthreads();
#pragma unroll
        for (int kk = 0; kk < 2; ++kk) {
            bf16x8 af[4], bfr[4];
#pragma unroll
            for (int t = 0; t < 4; ++t) {
                af[t] = frag_f32(Asf, wr + t * 16 + lr, lg * 8 + kk * 32);
                bfr[t] = lds_frag(Bs, wc + t * 16 + lr, lg * 16 + kk * 64);
            }
#pragma unroll
            for (int i = 0; i < 4; ++i)
#pragma unroll
                for (int j = 0; j < 4; ++j)
                    acc[i][j] = __builtin_amdgcn_mfma_f32_16x16x32_bf16(
                        af[i], bfr[j], acc[i][j], 0, 0, 0);
        }
    }
#pragma unroll
    for (int i = 0; i < 4; ++i) {
        int mb = m0 + wr + i * 16 + lg * 4;
        int b = mb >> 11, s = mb & 2047;
#pragma unroll
        for (int j = 0; j < 4; ++j) {
            int n = n0 + wc + j * 16 + lr;
            float bvv = bias[n];
            int h = n >> 6, e = n & 63;
            int bh = b * 16 + h;
            if (z == 2) {
                size_t addr = ((size_t)bh * 32 + (s >> 6)) * 4096 + (e >> 5) * 2048 +
                              ((s >> 4) & 3) * 512 + ((s >> 3) & 1) * 256 +
                              (e & 31) * 8 + (s & 7);
                bf16x4 o;
#pragma unroll
                for (int r = 0; r < 4; ++r) o[r] = (__bf16)(acc[i][j][r] + bvv);
                *(bf16x4*)(Vp + addr) = o;
            } else {
                __bf16* out = z == 0 ? Qp : Kp;
                size_t base = ((size_t)bh * 64 + (s >> 5)) * 2048 + (e >> 4) * 512 +
                              ((e >> 3) & 1) * 256 + (s & 31) * 8 + (e & 7);
#pragma unroll
                for (int r = 0; r < 4; ++r)
                    out[base + r * 8] = (__bf16)((acc[i][j][r] + bvv) * sc);
            }
        }
    }
}

// ---------------- final GEMM + GELU (grid: x=m 64, y=n 8; XCD = m%8) --------
__global__ __launch_bounds__(256) void gemm_out(const __bf16* __restrict__ A,
                                                const __bf16* __restrict__ Bt,
                                                const float* __restrict__ bias,
                                                float* __restrict__ dst) {
    __shared__ __bf16 As[64 * 64];
    __shared__ __bf16 Bs[128 * 64];
    int tid = threadIdx.x;
    int w = tid >> 6, lane = tid & 63, lg = lane >> 4, lr = lane & 15;
    int wr = (w >> 1) * 32, wc = (w & 1) * 64;
    int m0 = blockIdx.x * 64, n0 = blockIdx.y * 128;    // m fastest -> XCD=m%8
    f32x4 acc[2][4] = {};
    for (int k0 = 0; k0 < 1024; k0 += 64) {
        __syncthreads();
        stage_tile<64>(A + (size_t)m0 * 1024 + k0, 1024, As, tid);
        stage_tile<128>(Bt + (size_t)n0 * 1024 + k0, 1024, Bs, tid);
        __syncthreads();
#pragma unroll
        for (int kk = 0; kk < 2; ++kk) {
            bf16x8 af[2], bfr[4];
#pragma unroll
            for (int t = 0; t < 2; ++t)
                af[t] = lds_frag(As, wr + t * 16 + lr, lg * 16 + kk * 64);
#pragma unroll
            for (int t = 0; t < 4; ++t)
                bfr[t] = lds_frag(Bs, wc + t * 16 + lr, lg * 16 + kk * 64);
#pragma unroll
            for (int i = 0; i < 2; ++i)
#pragma unroll
                for (int j = 0; j < 4; ++j)
                    acc[i][j] = __builtin_amdgcn_mfma_f32_16x16x32_bf16(
                        af[i], bfr[j], acc[i][j], 0, 0, 0);
        }
    }
#pragma unroll
    for (int i = 0; i < 2; ++i) {
        int mb = m0 + wr + i * 16 + lg * 4;
#pragma unroll
        for (int j = 0; j < 4; ++j) {
            int n = n0 + wc + j * 16 + lr;
            float bvv = bias[n];
#pragma unroll
            for (int r = 0; r < 4; ++r) {
                float v = acc[i][j][r] + bvv;
                float g = v / (1.f + fexp2(GELC * v));
                dst[(size_t)(mb + r) * 1024 + n] = g;
            }
        }
    }
}

// ---------------- flash attention: LDS-free, fragment-packed streams --------
// 1D grid 1024, XCD decode. No barriers, no LDS. K reg-prefetched one tile
// ahead; V loads issued before exp2 block. Raw v_exp_f32 softmax (max-free).
__global__ __launch_bounds__(256) void attn_kernel(
    const __bf16* __restrict__ Qp, const __bf16* __restrict__ Kp,
    const __bf16* __restrict__ Vp, const float* __restrict__ mask,
    const unsigned* __restrict__ flags,
    __bf16* __restrict__ Op0, __bf16* __restrict__ Op1,
    float* __restrict__ lacc) {
    int tid = threadIdx.x;
    int w = tid >> 6, l = tid & 63;
    int q31 = l & 31, hi = l >> 5;
    int i = blockIdx.x;
    int xcd = i & 7, j = i >> 3;
    int group = (j >> 4) * 8 + xcd;
    int qt = j & 15;
    int bh = group & 31, z = group >> 5;
    int b = bh >> 4, h = bh & 15;
    int qw = qt * 128 + w * 32;

    // Q frags: per (b,h) block sb = qw/32; lane offset kk*512 + l*8
    const __bf16* Qb = Qp + ((size_t)bh * 64 + (qw >> 5)) * 2048 + l * 8;
    bf16x8 qf[4];
#pragma unroll
    for (int kk = 0; kk < 4; ++kk) qf[kk] = *(const bf16x8*)(Qb + kk * 512);

    const __bf16* Kb = Kp + ((size_t)bh * 64 + z * 32) * 2048 + l * 8;
    const __bf16* Vb = Vp + ((size_t)bh * 32 + z * 16) * 4096 + l * 8;
    const float* mrow = mask + (size_t)b * 4194304 + (size_t)(qw + q31) * 2048 + (z << 10) + hi * 4;
    const unsigned* flg = flags + (b * 16 + qt) * 32 + z * 16;

    f32x16 O[2] = {};
    float la0 = 0.f, la1 = 0.f;

    // K prefetch tile 0: sb = kt*2 + mt, frag at sb*2048 + kk*512
    bf16x8 kf[2][4];
#pragma unroll
    for (int mt = 0; mt < 2; ++mt)
#pragma unroll
        for (int kk = 0; kk < 4; ++kk)
            kf[mt][kk] = *(const bf16x8*)(Kb + (mt * 4 + kk) * 512);

    for (int kt = 0; kt < 16; ++kt) {
        f32x16 T[2] = {};
        __builtin_amdgcn_s_setprio(1);
#pragma unroll
        for (int kk = 0; kk < 4; ++kk)
#pragma unroll
            for (int mt = 0; mt < 2; ++mt)
                T[mt] = __builtin_amdgcn_mfma_f32_32x32x16_bf16(kf[mt][kk], qf[kk], T[mt], 0, 0, 0);
        __builtin_amdgcn_s_setprio(0);

        // V loads for this tile + K prefetch for next: in flight across exp2
        bf16x8 vf[2][4];
#pragma unroll
        for (int mt = 0; mt < 2; ++mt)
#pragma unroll
            for (int kk = 0; kk < 4; ++kk)
                vf[mt][kk] = *(const bf16x8*)(Vb + (size_t)kt * 4096 + (mt * 4 + kk) * 512);
        if (kt < 15) {
#pragma unroll
            for (int mt = 0; mt < 2; ++mt)
#pragma unroll
                for (int kk = 0; kk < 4; ++kk)
                    kf[mt][kk] = *(const bf16x8*)(Kb + ((size_t)(kt + 1) * 2 + mt) * 2048 + kk * 512);
        }

        // flag-gated mask add (wave-uniform branch), then max-free exp2
        unsigned fl = __builtin_amdgcn_readfirstlane(flg[kt]);
        if (fl) {
#pragma unroll
            for (int mt = 0; mt < 2; ++mt)
#pragma unroll
                for (int g = 0; g < 4; ++g) {
                    f32x4 mk = *(const f32x4*)(mrow + kt * 64 + mt * 32 + g * 8);
#pragma unroll
                    for (int c = 0; c < 4; ++c)
                        T[mt][4 * g + c] = fmaf(mk[c], L2E, T[mt][4 * g + c]);
                }
        }
#pragma unroll
        for (int g = 0; g < 4; ++g) {
            float a0 = fexp2(T[0][4 * g + 0]);
            float a1 = fexp2(T[0][4 * g + 1]);
            float a2 = fexp2(T[0][4 * g + 2]);
            float a3 = fexp2(T[0][4 * g + 3]);
            float b0 = fexp2(T[1][4 * g + 0]);
            float b1 = fexp2(T[1][4 * g + 1]);
            float b2 = fexp2(T[1][4 * g + 2]);
            float b3 = fexp2(T[1][4 * g + 3]);
            la0 += (a0 + a1) + (a2 + a3);
            la1 += (b0 + b1) + (b2 + b3);
            T[0][4 * g + 0] = a0; T[0][4 * g + 1] = a1;
            T[0][4 * g + 2] = a2; T[0][4 * g + 3] = a3;
            T[1][4 * g + 0] = b0; T[1][4 * g + 1] = b1;
            T[1][4 * g + 2] = b2; T[1][4 * g + 3] = b3;
        }

        // P frags in-register: pf[kk][j] = P[q=q31][kv = kk*16 + hi*8 + j]
        bf16x8 pf[4];
#pragma unroll
        for (int kk = 0; kk < 4; ++kk) {
            int mt = kk >> 1;
            int gA = (2 * kk) & 3, gB = gA + 1;
            unsigned x0 = cvtpk(T[mt][4 * gA + 0], T[mt][4 * gA + 1]);
            unsigned x1 = cvtpk(T[mt][4 * gA + 2], T[mt][4 * gA + 3]);
            unsigned y0 = cvtpk(T[mt][4 * gB + 0], T[mt][4 * gB + 1]);
            unsigned y1 = cvtpk(T[mt][4 * gB + 2], T[mt][4 * gB + 3]);
            pswap(x0, y0);
            pswap(x1, y1);
            u32x4 packed; packed[0] = x0; packed[1] = x1; packed[2] = y0; packed[3] = y1;
            pf[kk] = __builtin_bit_cast(bf16x8, packed);
        }

        __builtin_amdgcn_s_setprio(1);
#pragma unroll
        for (int kk = 0; kk < 4; ++kk)
#pragma unroll
            for (int mt = 0; mt < 2; ++mt)
                O[mt] = __builtin_amdgcn_mfma_f32_32x32x16_bf16(vf[mt][kk], pf[kk], O[mt], 0, 0, 0);
        __builtin_amdgcn_s_setprio(0);
    }

    // combine via plain coalesced stores (one writer per address)
    float l_acc = la0 + la1;
    l_acc += __shfl_xor(l_acc, 32, 64);
    if (hi == 0)
        lacc[((size_t)z * 32 + b * 16 + h) * 2048 + qw + q31] = l_acc;
    __bf16* Ob = (z ? Op1 : Op0) + (((size_t)(b * 16 + h)) * 2048 + qw + q31) * 64 + hi * 4;
#pragma unroll
    for (int mt = 0; mt < 2; ++mt)
#pragma unroll
        for (int g = 0; g < 4; ++g) {
            bf16x4 o;
#pragma unroll
            for (int c = 0; c < 4; ++c) o[c] = (__bf16)O[mt][4 * g + c];
            *(bf16x4*)(Ob + mt * 32 + g * 8) = o;
        }
}

// normalize: x[b,s,h*64+e] = bf16((Op0+Op1)[b][h][s][e] / (l0+l1)[b][h][s])
__global__ __launch_bounds__(256) void attn_norm(const __bf16* __restrict__ Op0,
                                                 const __bf16* __restrict__ Op1,
                                                 const float* __restrict__ lacc,
                                                 __bf16* __restrict__ x) {
    int idx = blockIdx.x * 256 + threadIdx.x;   // 1,048,576 total
    int b = idx >> 19;
    int rem = idx & 524287;                     // h[4] s[11] e4[4]
    int h = rem >> 15;
    int s = (rem >> 4) & 2047;
    int e0 = (rem & 15) * 4;
    size_t base = (((size_t)(b * 16 + h)) * 2048 + s) * 64 + e0;
    bf16x4 a = *(const bf16x4*)(Op0 + base);
    bf16x4 c = *(const bf16x4*)(Op1 + base);
    size_t li = ((size_t)(b * 16 + h)) * 2048 + s;
    float inv = 1.0f / (lacc[li] + lacc[65536 + li]);
    bf16x4 r;
#pragma unroll
    for (int j = 0; j < 4; ++j)
        r[j] = (__bf16)(((float)a[j] + (float)c[j]) * inv);
    *(bf16x4*)(x + ((size_t)b * 2048 + s) * 1024 + h * 64 + e0) = r;
}

// ---------------- launch ----------------

extern "C" void kernel_launch(void* const* d_in, const int* in_sizes, int n_in,
                              void* d_out, int out_size, void* d_ws, size_t ws_size,
                              hipStream_t stream) {
    const float* q    = (const float*)d_in[0];
    const float* k    = (const float*)d_in[1];
    const float* v    = (const float*)d_in[2];
    const float* mask = (const float*)d_in[3];
    const float* Wq   = (const float*)d_in[4];
    const float* bq   = (const float*)d_in[5];
    const float* Wk   = (const float*)d_in[6];
    const float* bk   = (const float*)d_in[7];
    const float* Wv   = (const float*)d_in[8];
    const float* bv   = (const float*)d_in[9];
    const float* Wo   = (const float*)d_in[10];
    const float* bo   = (const float*)d_in[11];

    char* ws = (char*)d_ws;
    __bf16* Op0 = (__bf16*)(ws + (0ull  << 20));
    __bf16* Op1 = (__bf16*)(ws + (8ull  << 20));
    __bf16* xp  = (__bf16*)(ws + (16ull << 20));
    __bf16* w3  = (__bf16*)(ws + (24ull << 20));   // 6 MB
    __bf16* wo  = (__bf16*)(ws + (30ull << 20));   // 2 MB
    __bf16* Qpk = (__bf16*)(ws + (32ull << 20));   // packed Q
    __bf16* Kpk = (__bf16*)(ws + (40ull << 20));   // packed K
    __bf16* Vpk = (__bf16*)(ws + (48ull << 20));   // packed V
    float*  laccp = (float*)(ws + (56ull << 20));                        // 512 KB
    unsigned* flagp = (unsigned*)(ws + (56ull << 20) + (512ull << 10));  // 4 KB

    pack_w4<<<dim3(16, 16, 4), 256, 0, stream>>>(Wq, Wk, Wv, Wo, w3, wo);
    hipMemsetAsync(flagp, 0, 4096, stream);
    mask_flags<<<8192, 256, 0, stream>>>(mask, flagp);

    gemm_qkv<<<dim3(32, 8, 3), 256, 0, stream>>>(q, k, v, w3, bq, bk, bv,
                                                 Qpk, Kpk, Vpk);

    attn_kernel<<<dim3(1024), 256, 0, stream>>>(Qpk, Kpk, Vpk, mask, flagp,
                                                Op0, Op1, laccp);
    attn_norm<<<4096, 256, 0, stream>>>(Op0, Op1, laccp, xp);

    gemm_out<<<dim3(64, 8), 256, 0, stream>>>(xp, wo, bo, (float*)d_out);
}

// Round 15
// 145.418 us; speedup vs baseline: 1.1100x; 1.0038x over previous
//
#include <hip/hip_runtime.h>
#include <stdint.h>

// MultiHeadedAttention: B=2,S=2048,D=1024,H=16,HD=64
// R15 = best-of composition: R11's bf16 gemm_qkv (+packed epilogue) + cvt3
// (roofline stream, both fusion attempts R12/R14 were net-negative) + R14's
// fexp2 attn (69->44us, VALU-bound fix) + fexp2 gemm_out + pack_w4 + flags.
// Workspace (MB): 0-8 qb->Op0, 8-16 kb->Op1, 16-24 vb->x, 24-30 w3, 30-32 wo,
// 32-40 Qp, 40-48 Kp, 48-56 Vp, 56+ lacc(512KB)+flags(4KB)

typedef __bf16 bf16x8 __attribute__((ext_vector_type(8)));
typedef __bf16 bf16x4 __attribute__((ext_vector_type(4)));
typedef float f32x4 __attribute__((ext_vector_type(4)));
typedef float f32x16 __attribute__((ext_vector_type(16)));
typedef unsigned u32x4 __attribute__((ext_vector_type(4)));

static constexpr float L2E  = 1.4426950408889634f;
static constexpr float QSCL = 0.18033688011112042f;   // 0.125 * log2(e)
static constexpr float GELC = -2.4554669595930157f;   // -1.702 * log2(e)

#if __has_builtin(__builtin_amdgcn_exp2f)
__device__ __forceinline__ float fexp2(float x) { return __builtin_amdgcn_exp2f(x); }
#else
__device__ __forceinline__ float fexp2(float x) {
    float r; asm("v_exp_f32 %0, %1" : "=v"(r) : "v"(x)); return r;
}
#endif

__device__ __forceinline__ void async_load16(const void* g, void* l) {
    __builtin_amdgcn_global_load_lds(
        (const __attribute__((address_space(1))) unsigned int*)(uintptr_t)g,
        (__attribute__((address_space(3))) unsigned int*)(unsigned int)(uintptr_t)l,
        16, 0, 0);
}

// Stage ROWS x 64-bf16 tile into LDS, phys = row*128 + (kb ^ ((row&7)<<4)).
template <int ROWS>
__device__ __forceinline__ void stage_tile(const __bf16* g, int ld, __bf16* lds, int tid) {
#pragma unroll
    for (int r = 0; r < ROWS / 32; ++r) {
        int p = r * 4096 + tid * 16;
        int row = p >> 7;
        int kbp = p & 127;
        int kbl = kbp ^ ((row & 7) << 4);
        async_load16((const char*)(g + (size_t)row * ld) + kbl,
                     (char*)lds + (p & ~1023));
    }
}

__device__ __forceinline__ bf16x8 lds_frag(const __bf16* base, int row, int kb) {
    return *(const bf16x8*)((const char*)base + (row << 7) + (kb ^ ((row & 7) << 4)));
}

__device__ __forceinline__ unsigned cvtpk(float a, float b) {
    unsigned d;
    asm("v_cvt_pk_bf16_f32 %0, %1, %2" : "=v"(d) : "v"(a), "v"(b));
    return d;
}
__device__ __forceinline__ void pswap(unsigned& a, unsigned& b) {
    asm("v_permlane32_swap_b32 %0, %1" : "+v"(a), "+v"(b));
}

// ---------------- prep kernels ----------------

__global__ __launch_bounds__(256) void cvt3_kernel(const float* __restrict__ q,
                                                   const float* __restrict__ k,
                                                   const float* __restrict__ v,
                                                   __bf16* __restrict__ qb,
                                                   __bf16* __restrict__ kb,
                                                   __bf16* __restrict__ vb) {
    int z = blockIdx.y;
    const float* src = z == 0 ? q : (z == 1 ? k : v);
    __bf16* dst = z == 0 ? qb : (z == 1 ? kb : vb);
    int i = blockIdx.x * 256 + threadIdx.x;
    f32x4 val = ((const f32x4*)src)[i];
    bf16x4 o;
    o[0] = (__bf16)val[0]; o[1] = (__bf16)val[1];
    o[2] = (__bf16)val[2]; o[3] = (__bf16)val[3];
    ((bf16x4*)dst)[i] = o;
}

// Per-(b, q/128, kv/64) nonzero flags from the f32 mask (zero mask => 0 atomics)
__global__ __launch_bounds__(256) void mask_flags(const float* __restrict__ m,
                                                  unsigned* __restrict__ flags) {
    int i = blockIdx.x * 256 + threadIdx.x;    // over B*S*S/4 = 2,097,152
    f32x4 v = ((const f32x4*)m)[i];
    bool nz = (v[0] != 0.f) | (v[1] != 0.f) | (v[2] != 0.f) | (v[3] != 0.f);
    if (nz) {
        size_t i4 = (size_t)i * 4;
        int b = (int)(i4 >> 22);
        int rem = (int)(i4 & 4194303);
        int qq = rem >> 11, kv = rem & 2047;
        atomicOr(flags + (b * 16 + (qq >> 7)) * 32 + (kv >> 6), 1u);
    }
}

// z<3: Wq/Wk/Wv [H][D][HD] -> w3[z][n][k]; z==3: Wo [K][N] -> wo[n][k]
__global__ __launch_bounds__(256) void pack_w4(const float* __restrict__ Wq,
                                               const float* __restrict__ Wk,
                                               const float* __restrict__ Wv,
                                               const float* __restrict__ Wo,
                                               __bf16* __restrict__ w3,
                                               __bf16* __restrict__ wo) {
    __shared__ __bf16 T[64][72];
    int tid = threadIdx.x;
    int z = blockIdx.z;
    int k0 = blockIdx.x * 64;
    if (z < 3) {
        int h = blockIdx.y;
        const float* W = z == 0 ? Wq : (z == 1 ? Wk : Wv);
#pragma unroll
        for (int it = 0; it < 4; ++it) {
            int idx = it * 1024 + tid * 4;
            int r = idx >> 6, e = idx & 63;
            f32x4 val = *(const f32x4*)(W + ((size_t)h * 1024 + k0 + r) * 64 + e);
#pragma unroll
            for (int j = 0; j < 4; ++j) T[r][e + j] = (__bf16)val[j];
        }
        __syncthreads();
        int e2 = tid >> 2, kc = (tid & 3) * 16;
        bf16x8 o0, o1;
#pragma unroll
        for (int i = 0; i < 8; ++i) { o0[i] = T[kc + i][e2]; o1[i] = T[kc + 8 + i][e2]; }
        __bf16* dst = w3 + ((size_t)z << 20) + (size_t)(h * 64 + e2) * 1024 + k0 + kc;
        *(bf16x8*)dst = o0;
        *(bf16x8*)(dst + 8) = o1;
    } else {
        int n0 = blockIdx.y * 64;
#pragma unroll
        for (int it = 0; it < 4; ++it) {
            int idx = it * 1024 + tid * 4;
            int r = idx >> 6, e = idx & 63;
            f32x4 val = *(const f32x4*)(Wo + (size_t)(k0 + r) * 1024 + n0 + e);
#pragma unroll
            for (int j = 0; j < 4; ++j) T[r][e + j] = (__bf16)val[j];
        }
        __syncthreads();
        int e2 = tid >> 2, kc = (tid & 3) * 16;
        bf16x8 o0, o1;
#pragma unroll
        for (int i = 0; i < 8; ++i) { o0[i] = T[kc + i][e2]; o1[i] = T[kc + 8 + i][e2]; }
        __bf16* dst = wo + (size_t)(n0 + e2) * 1024 + k0 + kc;
        *(bf16x8*)dst = o0;
        *(bf16x8*)(dst + 8) = o1;
    }
}

// ---------------- fused QKV GEMM + fragment-pack epilogue (R11) -------------
// grid (x=m 32, y=n 8, z=3; XCD = m%8).
// z=0/1: write Q/K packed per (b,h): [s/32][kk][hi][q31][8]
// z=2:   write V packed per (b,h): [s/64][mt][kk][hi][e31][8] (bf16x4 stores)
__global__ __launch_bounds__(256) void gemm_qkv(
    const __bf16* __restrict__ qb, const __bf16* __restrict__ kb,
    const __bf16* __restrict__ vb, const __bf16* __restrict__ w3,
    const float* __restrict__ bq, const float* __restrict__ bk,
    const float* __restrict__ bv,
    __bf16* __restrict__ Qp, __bf16* __restrict__ Kp, __bf16* __restrict__ Vp) {
    __shared__ __bf16 As[128 * 64];
    __shared__ __bf16 Bs[128 * 64];
    int z = blockIdx.z;
    const __bf16* A = z == 0 ? qb : (z == 1 ? kb : vb);
    const __bf16* Bt = w3 + ((size_t)z << 20);
    const float* bias = z == 0 ? bq : (z == 1 ? bk : bv);
    float sc = z == 0 ? QSCL : 1.0f;

    int tid = threadIdx.x;
    int w = tid >> 6, lane = tid & 63, lg = lane >> 4, lr = lane & 15;
    int wr = (w >> 1) * 64, wc = (w & 1) * 64;
    int m0 = blockIdx.x * 128, n0 = blockIdx.y * 128;   // m fastest -> XCD=m%8
    f32x4 acc[4][4] = {};
    for (int k0 = 0; k0 < 1024; k0 += 64) {
        __syncthreads();
        stage_tile<128>(A + (size_t)m0 * 1024 + k0, 1024, As, tid);
        stage_tile<128>(Bt + (size_t)n0 * 1024 + k0, 1024, Bs, tid);
        __syncthreads();
#pragma unroll
        for (int kk = 0; kk < 2; ++kk) {
            bf16x8 af[4], bfr[4];
#pragma unroll
            for (int t = 0; t < 4; ++t) {
                af[t] = lds_frag(As, wr + t * 16 + lr, lg * 16 + kk * 64);
                bfr[t] = lds_frag(Bs, wc + t * 16 + lr, lg * 16 + kk * 64);
            }
#pragma unroll
            for (int i = 0; i < 4; ++i)
#pragma unroll
                for (int j = 0; j < 4; ++j)
                    acc[i][j] = __builtin_amdgcn_mfma_f32_16x16x32_bf16(
                        af[i], bfr[j], acc[i][j], 0, 0, 0);
        }
    }
#pragma unroll
    for (int i = 0; i < 4; ++i) {
        int mb = m0 + wr + i * 16 + lg * 4;
        int b = mb >> 11, s = mb & 2047;
#pragma unroll
        for (int j = 0; j < 4; ++j) {
            int n = n0 + wc + j * 16 + lr;
            float bvv = bias[n];
            int h = n >> 6, e = n & 63;
            int bh = b * 16 + h;
            if (z == 2) {
                size_t addr = ((size_t)bh * 32 + (s >> 6)) * 4096 + (e >> 5) * 2048 +
                              ((s >> 4) & 3) * 512 + ((s >> 3) & 1) * 256 +
                              (e & 31) * 8 + (s & 7);
                bf16x4 o;
#pragma unroll
                for (int r = 0; r < 4; ++r) o[r] = (__bf16)(acc[i][j][r] + bvv);
                *(bf16x4*)(Vp + addr) = o;
            } else {
                __bf16* out = z == 0 ? Qp : Kp;
                size_t base = ((size_t)bh * 64 + (s >> 5)) * 2048 + (e >> 4) * 512 +
                              ((e >> 3) & 1) * 256 + (s & 31) * 8 + (e & 7);
#pragma unroll
                for (int r = 0; r < 4; ++r)
                    out[base + r * 8] = (__bf16)((acc[i][j][r] + bvv) * sc);
            }
        }
    }
}

// ---------------- final GEMM + GELU (grid: x=m 64, y=n 8; XCD = m%8) --------
__global__ __launch_bounds__(256) void gemm_out(const __bf16* __restrict__ A,
                                                const __bf16* __restrict__ Bt,
                                                const float* __restrict__ bias,
                                                float* __restrict__ dst) {
    __shared__ __bf16 As[64 * 64];
    __shared__ __bf16 Bs[128 * 64];
    int tid = threadIdx.x;
    int w = tid >> 6, lane = tid & 63, lg = lane >> 4, lr = lane & 15;
    int wr = (w >> 1) * 32, wc = (w & 1) * 64;
    int m0 = blockIdx.x * 64, n0 = blockIdx.y * 128;    // m fastest -> XCD=m%8
    f32x4 acc[2][4] = {};
    for (int k0 = 0; k0 < 1024; k0 += 64) {
        __syncthreads();
        stage_tile<64>(A + (size_t)m0 * 1024 + k0, 1024, As, tid);
        stage_tile<128>(Bt + (size_t)n0 * 1024 + k0, 1024, Bs, tid);
        __syncthreads();
#pragma unroll
        for (int kk = 0; kk < 2; ++kk) {
            bf16x8 af[2], bfr[4];
#pragma unroll
            for (int t = 0; t < 2; ++t)
                af[t] = lds_frag(As, wr + t * 16 + lr, lg * 16 + kk * 64);
#pragma unroll
            for (int t = 0; t < 4; ++t)
                bfr[t] = lds_frag(Bs, wc + t * 16 + lr, lg * 16 + kk * 64);
#pragma unroll
            for (int i = 0; i < 2; ++i)
#pragma unroll
                for (int j = 0; j < 4; ++j)
                    acc[i][j] = __builtin_amdgcn_mfma_f32_16x16x32_bf16(
                        af[i], bfr[j], acc[i][j], 0, 0, 0);
        }
    }
#pragma unroll
    for (int i = 0; i < 2; ++i) {
        int mb = m0 + wr + i * 16 + lg * 4;
#pragma unroll
        for (int j = 0; j < 4; ++j) {
            int n = n0 + wc + j * 16 + lr;
            float bvv = bias[n];
#pragma unroll
            for (int r = 0; r < 4; ++r) {
                float v = acc[i][j][r] + bvv;
                float g = v / (1.f + fexp2(GELC * v));
                dst[(size_t)(mb + r) * 1024 + n] = g;
            }
        }
    }
}

// ---------------- flash attention: LDS-free, fragment-packed streams --------
// 1D grid 1024, XCD decode. No barriers, no LDS. K reg-prefetched one tile
// ahead; V loads issued before exp2 block. Raw v_exp_f32 softmax (max-free).
__global__ __launch_bounds__(256) void attn_kernel(
    const __bf16* __restrict__ Qp, const __bf16* __restrict__ Kp,
    const __bf16* __restrict__ Vp, const float* __restrict__ mask,
    const unsigned* __restrict__ flags,
    __bf16* __restrict__ Op0, __bf16* __restrict__ Op1,
    float* __restrict__ lacc) {
    int tid = threadIdx.x;
    int w = tid >> 6, l = tid & 63;
    int q31 = l & 31, hi = l >> 5;
    int i = blockIdx.x;
    int xcd = i & 7, j = i >> 3;
    int group = (j >> 4) * 8 + xcd;
    int qt = j & 15;
    int bh = group & 31, z = group >> 5;
    int b = bh >> 4, h = bh & 15;
    int qw = qt * 128 + w * 32;

    // Q frags: per (b,h) block sb = qw/32; lane offset kk*512 + l*8
    const __bf16* Qb = Qp + ((size_t)bh * 64 + (qw >> 5)) * 2048 + l * 8;
    bf16x8 qf[4];
#pragma unroll
    for (int kk = 0; kk < 4; ++kk) qf[kk] = *(const bf16x8*)(Qb + kk * 512);

    const __bf16* Kb = Kp + ((size_t)bh * 64 + z * 32) * 2048 + l * 8;
    const __bf16* Vb = Vp + ((size_t)bh * 32 + z * 16) * 4096 + l * 8;
    const float* mrow = mask + (size_t)b * 4194304 + (size_t)(qw + q31) * 2048 + (z << 10) + hi * 4;
    const unsigned* flg = flags + (b * 16 + qt) * 32 + z * 16;

    f32x16 O[2] = {};
    float la0 = 0.f, la1 = 0.f;

    // K prefetch tile 0: sb = kt*2 + mt, frag at sb*2048 + kk*512
    bf16x8 kf[2][4];
#pragma unroll
    for (int mt = 0; mt < 2; ++mt)
#pragma unroll
        for (int kk = 0; kk < 4; ++kk)
            kf[mt][kk] = *(const bf16x8*)(Kb + (mt * 4 + kk) * 512);

    for (int kt = 0; kt < 16; ++kt) {
        f32x16 T[2] = {};
        __builtin_amdgcn_s_setprio(1);
#pragma unroll
        for (int kk = 0; kk < 4; ++kk)
#pragma unroll
            for (int mt = 0; mt < 2; ++mt)
                T[mt] = __builtin_amdgcn_mfma_f32_32x32x16_bf16(kf[mt][kk], qf[kk], T[mt], 0, 0, 0);
        __builtin_amdgcn_s_setprio(0);

        // V loads for this tile + K prefetch for next: in flight across exp2
        bf16x8 vf[2][4];
#pragma unroll
        for (int mt = 0; mt < 2; ++mt)
#pragma unroll
            for (int kk = 0; kk < 4; ++kk)
                vf[mt][kk] = *(const bf16x8*)(Vb + (size_t)kt * 4096 + (mt * 4 + kk) * 512);
        if (kt < 15) {
#pragma unroll
            for (int mt = 0; mt < 2; ++mt)
#pragma unroll
                for (int kk = 0; kk < 4; ++kk)
                    kf[mt][kk] = *(const bf16x8*)(Kb + ((size_t)(kt + 1) * 2 + mt) * 2048 + kk * 512);
        }

        // flag-gated mask add (wave-uniform branch), then max-free exp2
        unsigned fl = __builtin_amdgcn_readfirstlane(flg[kt]);
        if (fl) {
#pragma unroll
            for (int mt = 0; mt < 2; ++mt)
#pragma unroll
                for (int g = 0; g < 4; ++g) {
                    f32x4 mk = *(const f32x4*)(mrow + kt * 64 + mt * 32 + g * 8);
#pragma unroll
                    for (int c = 0; c < 4; ++c)
                        T[mt][4 * g + c] = fmaf(mk[c], L2E, T[mt][4 * g + c]);
                }
        }
#pragma unroll
        for (int g = 0; g < 4; ++g) {
            float a0 = fexp2(T[0][4 * g + 0]);
            float a1 = fexp2(T[0][4 * g + 1]);
            float a2 = fexp2(T[0][4 * g + 2]);
            float a3 = fexp2(T[0][4 * g + 3]);
            float b0 = fexp2(T[1][4 * g + 0]);
            float b1 = fexp2(T[1][4 * g + 1]);
            float b2 = fexp2(T[1][4 * g + 2]);
            float b3 = fexp2(T[1][4 * g + 3]);
            la0 += (a0 + a1) + (a2 + a3);
            la1 += (b0 + b1) + (b2 + b3);
            T[0][4 * g + 0] = a0; T[0][4 * g + 1] = a1;
            T[0][4 * g + 2] = a2; T[0][4 * g + 3] = a3;
            T[1][4 * g + 0] = b0; T[1][4 * g + 1] = b1;
            T[1][4 * g + 2] = b2; T[1][4 * g + 3] = b3;
        }

        // P frags in-register: pf[kk][j] = P[q=q31][kv = kk*16 + hi*8 + j]
        bf16x8 pf[4];
#pragma unroll
        for (int kk = 0; kk < 4; ++kk) {
            int mt = kk >> 1;
            int gA = (2 * kk) & 3, gB = gA + 1;
            unsigned x0 = cvtpk(T[mt][4 * gA + 0], T[mt][4 * gA + 1]);
            unsigned x1 = cvtpk(T[mt][4 * gA + 2], T[mt][4 * gA + 3]);
            unsigned y0 = cvtpk(T[mt][4 * gB + 0], T[mt][4 * gB + 1]);
            unsigned y1 = cvtpk(T[mt][4 * gB + 2], T[mt][4 * gB + 3]);
            pswap(x0, y0);
            pswap(x1, y1);
            u32x4 packed; packed[0] = x0; packed[1] = x1; packed[2] = y0; packed[3] = y1;
            pf[kk] = __builtin_bit_cast(bf16x8, packed);
        }

        __builtin_amdgcn_s_setprio(1);
#pragma unroll
        for (int kk = 0; kk < 4; ++kk)
#pragma unroll
            for (int mt = 0; mt < 2; ++mt)
                O[mt] = __builtin_amdgcn_mfma_f32_32x32x16_bf16(vf[mt][kk], pf[kk], O[mt], 0, 0, 0);
        __builtin_amdgcn_s_setprio(0);
    }

    // combine via plain coalesced stores (one writer per address)
    float l_acc = la0 + la1;
    l_acc += __shfl_xor(l_acc, 32, 64);
    if (hi == 0)
        lacc[((size_t)z * 32 + b * 16 + h) * 2048 + qw + q31] = l_acc;
    __bf16* Ob = (z ? Op1 : Op0) + (((size_t)(b * 16 + h)) * 2048 + qw + q31) * 64 + hi * 4;
#pragma unroll
    for (int mt = 0; mt < 2; ++mt)
#pragma unroll
        for (int g = 0; g < 4; ++g) {
            bf16x4 o;
#pragma unroll
            for (int c = 0; c < 4; ++c) o[c] = (__bf16)O[mt][4 * g + c];
            *(bf16x4*)(Ob + mt * 32 + g * 8) = o;
        }
}

// normalize: x[b,s,h*64+e] = bf16((Op0+Op1)[b][h][s][e] / (l0+l1)[b][h][s])
__global__ __launch_bounds__(256) void attn_norm(const __bf16* __restrict__ Op0,
                                                 const __bf16* __restrict__ Op1,
                                                 const float* __restrict__ lacc,
                                                 __bf16* __restrict__ x) {
    int idx = blockIdx.x * 256 + threadIdx.x;   // 1,048,576 total
    int b = idx >> 19;
    int rem = idx & 524287;                     // h[4] s[11] e4[4]
    int h = rem >> 15;
    int s = (rem >> 4) & 2047;
    int e0 = (rem & 15) * 4;
    size_t base = (((size_t)(b * 16 + h)) * 2048 + s) * 64 + e0;
    bf16x4 a = *(const bf16x4*)(Op0 + base);
    bf16x4 c = *(const bf16x4*)(Op1 + base);
    size_t li = ((size_t)(b * 16 + h)) * 2048 + s;
    float inv = 1.0f / (lacc[li] + lacc[65536 + li]);
    bf16x4 r;
#pragma unroll
    for (int j = 0; j < 4; ++j)
        r[j] = (__bf16)(((float)a[j] + (float)c[j]) * inv);
    *(bf16x4*)(x + ((size_t)b * 2048 + s) * 1024 + h * 64 + e0) = r;
}

// ---------------- launch ----------------

extern "C" void kernel_launch(void* const* d_in, const int* in_sizes, int n_in,
                              void* d_out, int out_size, void* d_ws, size_t ws_size,
                              hipStream_t stream) {
    const float* q    = (const float*)d_in[0];
    const float* k    = (const float*)d_in[1];
    const float* v    = (const float*)d_in[2];
    const float* mask = (const float*)d_in[3];
    const float* Wq   = (const float*)d_in[4];
    const float* bq   = (const float*)d_in[5];
    const float* Wk   = (const float*)d_in[6];
    const float* bk   = (const float*)d_in[7];
    const float* Wv   = (const float*)d_in[8];
    const float* bv   = (const float*)d_in[9];
    const float* Wo   = (const float*)d_in[10];
    const float* bo   = (const float*)d_in[11];

    char* ws = (char*)d_ws;
    __bf16* qb  = (__bf16*)(ws + (0ull  << 20));   // -> Op0 after gemm_qkv
    __bf16* kb  = (__bf16*)(ws + (8ull  << 20));   // -> Op1 after gemm_qkv
    __bf16* vb  = (__bf16*)(ws + (16ull << 20));   // -> x   after gemm_qkv
    __bf16* w3  = (__bf16*)(ws + (24ull << 20));   // 6 MB
    __bf16* wo  = (__bf16*)(ws + (30ull << 20));   // 2 MB
    __bf16* Qpk = (__bf16*)(ws + (32ull << 20));   // packed Q
    __bf16* Kpk = (__bf16*)(ws + (40ull << 20));   // packed K
    __bf16* Vpk = (__bf16*)(ws + (48ull << 20));   // packed V
    float*  laccp = (float*)(ws + (56ull << 20));                        // 512 KB
    unsigned* flagp = (unsigned*)(ws + (56ull << 20) + (512ull << 10));  // 4 KB
    __bf16* Op0 = qb;
    __bf16* Op1 = kb;
    __bf16* xp  = vb;

    cvt3_kernel<<<dim3(4096, 3), 256, 0, stream>>>(q, k, v, qb, kb, vb);
    pack_w4<<<dim3(16, 16, 4), 256, 0, stream>>>(Wq, Wk, Wv, Wo, w3, wo);
    hipMemsetAsync(flagp, 0, 4096, stream);
    mask_flags<<<8192, 256, 0, stream>>>(mask, flagp);

    gemm_qkv<<<dim3(32, 8, 3), 256, 0, stream>>>(qb, kb, vb, w3, bq, bk, bv,
                                                 Qpk, Kpk, Vpk);

    attn_kernel<<<dim3(1024), 256, 0, stream>>>(Qpk, Kpk, Vpk, mask, flagp,
                                                Op0, Op1, laccp);
    attn_norm<<<4096, 256, 0, stream>>>(Op0, Op1, laccp, xp);

    gemm_out<<<dim3(64, 8), 256, 0, stream>>>(xp, wo, bo, (float*)d_out);
}

// Round 16
// 144.975 us; speedup vs baseline: 1.1134x; 1.0031x over previous
//
#include <hip/hip_runtime.h>
#include <stdint.h>

// MultiHeadedAttention: B=2,S=2048,D=1024,H=16,HD=64
// R16 = R15 with ONE attn change: V-fragment loads moved to the TOP of each
// kv-tile (issued before the QK^T MFMA cluster). Load-to-use distance for the
// 8 V loads grows ~150 -> ~350-450 cyc, covering L2 latency that previously
// stalled PV entry (~70-100 cyc/tile/wave). Zero cost: no extra VGPR, no
// structural change. All other kernels identical to R15 (145.4us, 2.4e-4).
// Workspace (MB): 0-8 qb->Op0, 8-16 kb->Op1, 16-24 vb->x, 24-30 w3, 30-32 wo,
// 32-40 Qp, 40-48 Kp, 48-56 Vp, 56+ lacc(512KB)+flags(4KB)

typedef __bf16 bf16x8 __attribute__((ext_vector_type(8)));
typedef __bf16 bf16x4 __attribute__((ext_vector_type(4)));
typedef float f32x4 __attribute__((ext_vector_type(4)));
typedef float f32x16 __attribute__((ext_vector_type(16)));
typedef unsigned u32x4 __attribute__((ext_vector_type(4)));

static constexpr float L2E  = 1.4426950408889634f;
static constexpr float QSCL = 0.18033688011112042f;   // 0.125 * log2(e)
static constexpr float GELC = -2.4554669595930157f;   // -1.702 * log2(e)

#if __has_builtin(__builtin_amdgcn_exp2f)
__device__ __forceinline__ float fexp2(float x) { return __builtin_amdgcn_exp2f(x); }
#else
__device__ __forceinline__ float fexp2(float x) {
    float r; asm("v_exp_f32 %0, %1" : "=v"(r) : "v"(x)); return r;
}
#endif

__device__ __forceinline__ void async_load16(const void* g, void* l) {
    __builtin_amdgcn_global_load_lds(
        (const __attribute__((address_space(1))) unsigned int*)(uintptr_t)g,
        (__attribute__((address_space(3))) unsigned int*)(unsigned int)(uintptr_t)l,
        16, 0, 0);
}

// Stage ROWS x 64-bf16 tile into LDS, phys = row*128 + (kb ^ ((row&7)<<4)).
template <int ROWS>
__device__ __forceinline__ void stage_tile(const __bf16* g, int ld, __bf16* lds, int tid) {
#pragma unroll
    for (int r = 0; r < ROWS / 32; ++r) {
        int p = r * 4096 + tid * 16;
        int row = p >> 7;
        int kbp = p & 127;
        int kbl = kbp ^ ((row & 7) << 4);
        async_load16((const char*)(g + (size_t)row * ld) + kbl,
                     (char*)lds + (p & ~1023));
    }
}

__device__ __forceinline__ bf16x8 lds_frag(const __bf16* base, int row, int kb) {
    return *(const bf16x8*)((const char*)base + (row << 7) + (kb ^ ((row & 7) << 4)));
}

__device__ __forceinline__ unsigned cvtpk(float a, float b) {
    unsigned d;
    asm("v_cvt_pk_bf16_f32 %0, %1, %2" : "=v"(d) : "v"(a), "v"(b));
    return d;
}
__device__ __forceinline__ void pswap(unsigned& a, unsigned& b) {
    asm("v_permlane32_swap_b32 %0, %1" : "+v"(a), "+v"(b));
}

// ---------------- prep kernels ----------------

__global__ __launch_bounds__(256) void cvt3_kernel(const float* __restrict__ q,
                                                   const float* __restrict__ k,
                                                   const float* __restrict__ v,
                                                   __bf16* __restrict__ qb,
                                                   __bf16* __restrict__ kb,
                                                   __bf16* __restrict__ vb) {
    int z = blockIdx.y;
    const float* src = z == 0 ? q : (z == 1 ? k : v);
    __bf16* dst = z == 0 ? qb : (z == 1 ? kb : vb);
    int i = blockIdx.x * 256 + threadIdx.x;
    f32x4 val = ((const f32x4*)src)[i];
    bf16x4 o;
    o[0] = (__bf16)val[0]; o[1] = (__bf16)val[1];
    o[2] = (__bf16)val[2]; o[3] = (__bf16)val[3];
    ((bf16x4*)dst)[i] = o;
}

// Per-(b, q/128, kv/64) nonzero flags from the f32 mask (zero mask => 0 atomics)
__global__ __launch_bounds__(256) void mask_flags(const float* __restrict__ m,
                                                  unsigned* __restrict__ flags) {
    int i = blockIdx.x * 256 + threadIdx.x;    // over B*S*S/4 = 2,097,152
    f32x4 v = ((const f32x4*)m)[i];
    bool nz = (v[0] != 0.f) | (v[1] != 0.f) | (v[2] != 0.f) | (v[3] != 0.f);
    if (nz) {
        size_t i4 = (size_t)i * 4;
        int b = (int)(i4 >> 22);
        int rem = (int)(i4 & 4194303);
        int qq = rem >> 11, kv = rem & 2047;
        atomicOr(flags + (b * 16 + (qq >> 7)) * 32 + (kv >> 6), 1u);
    }
}

// z<3: Wq/Wk/Wv [H][D][HD] -> w3[z][n][k]; z==3: Wo [K][N] -> wo[n][k]
__global__ __launch_bounds__(256) void pack_w4(const float* __restrict__ Wq,
                                               const float* __restrict__ Wk,
                                               const float* __restrict__ Wv,
                                               const float* __restrict__ Wo,
                                               __bf16* __restrict__ w3,
                                               __bf16* __restrict__ wo) {
    __shared__ __bf16 T[64][72];
    int tid = threadIdx.x;
    int z = blockIdx.z;
    int k0 = blockIdx.x * 64;
    if (z < 3) {
        int h = blockIdx.y;
        const float* W = z == 0 ? Wq : (z == 1 ? Wk : Wv);
#pragma unroll
        for (int it = 0; it < 4; ++it) {
            int idx = it * 1024 + tid * 4;
            int r = idx >> 6, e = idx & 63;
            f32x4 val = *(const f32x4*)(W + ((size_t)h * 1024 + k0 + r) * 64 + e);
#pragma unroll
            for (int j = 0; j < 4; ++j) T[r][e + j] = (__bf16)val[j];
        }
        __syncthreads();
        int e2 = tid >> 2, kc = (tid & 3) * 16;
        bf16x8 o0, o1;
#pragma unroll
        for (int i = 0; i < 8; ++i) { o0[i] = T[kc + i][e2]; o1[i] = T[kc + 8 + i][e2]; }
        __bf16* dst = w3 + ((size_t)z << 20) + (size_t)(h * 64 + e2) * 1024 + k0 + kc;
        *(bf16x8*)dst = o0;
        *(bf16x8*)(dst + 8) = o1;
    } else {
        int n0 = blockIdx.y * 64;
#pragma unroll
        for (int it = 0; it < 4; ++it) {
            int idx = it * 1024 + tid * 4;
            int r = idx >> 6, e = idx & 63;
            f32x4 val = *(const f32x4*)(Wo + (size_t)(k0 + r) * 1024 + n0 + e);
#pragma unroll
            for (int j = 0; j < 4; ++j) T[r][e + j] = (__bf16)val[j];
        }
        __syncthreads();
        int e2 = tid >> 2, kc = (tid & 3) * 16;
        bf16x8 o0, o1;
#pragma unroll
        for (int i = 0; i < 8; ++i) { o0[i] = T[kc + i][e2]; o1[i] = T[kc + 8 + i][e2]; }
        __bf16* dst = wo + (size_t)(n0 + e2) * 1024 + k0 + kc;
        *(bf16x8*)dst = o0;
        *(bf16x8*)(dst + 8) = o1;
    }
}

// ---------------- fused QKV GEMM + fragment-pack epilogue -------------------
// grid (x=m 32, y=n 8, z=3; XCD = m%8).
__global__ __launch_bounds__(256) void gemm_qkv(
    const __bf16* __restrict__ qb, const __bf16* __restrict__ kb,
    const __bf16* __restrict__ vb, const __bf16* __restrict__ w3,
    const float* __restrict__ bq, const float* __restrict__ bk,
    const float* __restrict__ bv,
    __bf16* __restrict__ Qp, __bf16* __restrict__ Kp, __bf16* __restrict__ Vp) {
    __shared__ __bf16 As[128 * 64];
    __shared__ __bf16 Bs[128 * 64];
    int z = blockIdx.z;
    const __bf16* A = z == 0 ? qb : (z == 1 ? kb : vb);
    const __bf16* Bt = w3 + ((size_t)z << 20);
    const float* bias = z == 0 ? bq : (z == 1 ? bk : bv);
    float sc = z == 0 ? QSCL : 1.0f;

    int tid = threadIdx.x;
    int w = tid >> 6, lane = tid & 63, lg = lane >> 4, lr = lane & 15;
    int wr = (w >> 1) * 64, wc = (w & 1) * 64;
    int m0 = blockIdx.x * 128, n0 = blockIdx.y * 128;   // m fastest -> XCD=m%8
    f32x4 acc[4][4] = {};
    for (int k0 = 0; k0 < 1024; k0 += 64) {
        __syncthreads();
        stage_tile<128>(A + (size_t)m0 * 1024 + k0, 1024, As, tid);
        stage_tile<128>(Bt + (size_t)n0 * 1024 + k0, 1024, Bs, tid);
        __syncthreads();
#pragma unroll
        for (int kk = 0; kk < 2; ++kk) {
            bf16x8 af[4], bfr[4];
#pragma unroll
            for (int t = 0; t < 4; ++t) {
                af[t] = lds_frag(As, wr + t * 16 + lr, lg * 16 + kk * 64);
                bfr[t] = lds_frag(Bs, wc + t * 16 + lr, lg * 16 + kk * 64);
            }
#pragma unroll
            for (int i = 0; i < 4; ++i)
#pragma unroll
                for (int j = 0; j < 4; ++j)
                    acc[i][j] = __builtin_amdgcn_mfma_f32_16x16x32_bf16(
                        af[i], bfr[j], acc[i][j], 0, 0, 0);
        }
    }
#pragma unroll
    for (int i = 0; i < 4; ++i) {
        int mb = m0 + wr + i * 16 + lg * 4;
        int b = mb >> 11, s = mb & 2047;
#pragma unroll
        for (int j = 0; j < 4; ++j) {
            int n = n0 + wc + j * 16 + lr;
            float bvv = bias[n];
            int h = n >> 6, e = n & 63;
            int bh = b * 16 + h;
            if (z == 2) {
                size_t addr = ((size_t)bh * 32 + (s >> 6)) * 4096 + (e >> 5) * 2048 +
                              ((s >> 4) & 3) * 512 + ((s >> 3) & 1) * 256 +
                              (e & 31) * 8 + (s & 7);
                bf16x4 o;
#pragma unroll
                for (int r = 0; r < 4; ++r) o[r] = (__bf16)(acc[i][j][r] + bvv);
                *(bf16x4*)(Vp + addr) = o;
            } else {
                __bf16* out = z == 0 ? Qp : Kp;
                size_t base = ((size_t)bh * 64 + (s >> 5)) * 2048 + (e >> 4) * 512 +
                              ((e >> 3) & 1) * 256 + (s & 31) * 8 + (e & 7);
#pragma unroll
                for (int r = 0; r < 4; ++r)
                    out[base + r * 8] = (__bf16)((acc[i][j][r] + bvv) * sc);
            }
        }
    }
}

// ---------------- final GEMM + GELU (grid: x=m 64, y=n 8; XCD = m%8) --------
__global__ __launch_bounds__(256) void gemm_out(const __bf16* __restrict__ A,
                                                const __bf16* __restrict__ Bt,
                                                const float* __restrict__ bias,
                                                float* __restrict__ dst) {
    __shared__ __bf16 As[64 * 64];
    __shared__ __bf16 Bs[128 * 64];
    int tid = threadIdx.x;
    int w = tid >> 6, lane = tid & 63, lg = lane >> 4, lr = lane & 15;
    int wr = (w >> 1) * 32, wc = (w & 1) * 64;
    int m0 = blockIdx.x * 64, n0 = blockIdx.y * 128;    // m fastest -> XCD=m%8
    f32x4 acc[2][4] = {};
    for (int k0 = 0; k0 < 1024; k0 += 64) {
        __syncthreads();
        stage_tile<64>(A + (size_t)m0 * 1024 + k0, 1024, As, tid);
        stage_tile<128>(Bt + (size_t)n0 * 1024 + k0, 1024, Bs, tid);
        __syncthreads();
#pragma unroll
        for (int kk = 0; kk < 2; ++kk) {
            bf16x8 af[2], bfr[4];
#pragma unroll
            for (int t = 0; t < 2; ++t)
                af[t] = lds_frag(As, wr + t * 16 + lr, lg * 16 + kk * 64);
#pragma unroll
            for (int t = 0; t < 4; ++t)
                bfr[t] = lds_frag(Bs, wc + t * 16 + lr, lg * 16 + kk * 64);
#pragma unroll
            for (int i = 0; i < 2; ++i)
#pragma unroll
                for (int j = 0; j < 4; ++j)
                    acc[i][j] = __builtin_amdgcn_mfma_f32_16x16x32_bf16(
                        af[i], bfr[j], acc[i][j], 0, 0, 0);
        }
    }
#pragma unroll
    for (int i = 0; i < 2; ++i) {
        int mb = m0 + wr + i * 16 + lg * 4;
#pragma unroll
        for (int j = 0; j < 4; ++j) {
            int n = n0 + wc + j * 16 + lr;
            float bvv = bias[n];
#pragma unroll
            for (int r = 0; r < 4; ++r) {
                float v = acc[i][j][r] + bvv;
                float g = v / (1.f + fexp2(GELC * v));
                dst[(size_t)(mb + r) * 1024 + n] = g;
            }
        }
    }
}

// ---------------- flash attention: LDS-free, V loads hoisted to tile top ----
// 1D grid 1024, XCD decode. No barriers, no LDS. Per tile: issue V loads ->
// QK^T MFMA (kf) -> K prefetch (kt+1) -> exp2/pf -> PV (vf). V load-to-use
// now spans MFMA + exp2 (~350-450 cyc) covering L2 latency.
__global__ __launch_bounds__(256) void attn_kernel(
    const __bf16* __restrict__ Qp, const __bf16* __restrict__ Kp,
    const __bf16* __restrict__ Vp, const float* __restrict__ mask,
    const unsigned* __restrict__ flags,
    __bf16* __restrict__ Op0, __bf16* __restrict__ Op1,
    float* __restrict__ lacc) {
    int tid = threadIdx.x;
    int w = tid >> 6, l = tid & 63;
    int q31 = l & 31, hi = l >> 5;
    int i = blockIdx.x;
    int xcd = i & 7, j = i >> 3;
    int group = (j >> 4) * 8 + xcd;
    int qt = j & 15;
    int bh = group & 31, z = group >> 5;
    int b = bh >> 4, h = bh & 15;
    int qw = qt * 128 + w * 32;

    // Q frags: per (b,h) block sb = qw/32; lane offset kk*512 + l*8
    const __bf16* Qb = Qp + ((size_t)bh * 64 + (qw >> 5)) * 2048 + l * 8;
    bf16x8 qf[4];
#pragma unroll
    for (int kk = 0; kk < 4; ++kk) qf[kk] = *(const bf16x8*)(Qb + kk * 512);

    const __bf16* Kb = Kp + ((size_t)bh * 64 + z * 32) * 2048 + l * 8;
    const __bf16* Vb = Vp + ((size_t)bh * 32 + z * 16) * 4096 + l * 8;
    const float* mrow = mask + (size_t)b * 4194304 + (size_t)(qw + q31) * 2048 + (z << 10) + hi * 4;
    const unsigned* flg = flags + (b * 16 + qt) * 32 + z * 16;

    f32x16 O[2] = {};
    float la0 = 0.f, la1 = 0.f;

    // K prefetch tile 0: sb = kt*2 + mt, frag at sb*2048 + kk*512
    bf16x8 kf[2][4];
#pragma unroll
    for (int mt = 0; mt < 2; ++mt)
#pragma unroll
        for (int kk = 0; kk < 4; ++kk)
            kf[mt][kk] = *(const bf16x8*)(Kb + (mt * 4 + kk) * 512);

    for (int kt = 0; kt < 16; ++kt) {
        // V loads for THIS tile issued first: consumed only after exp2/pf,
        // so ~350-450 cycles of cover (MFMA + softmax) for L2 latency.
        bf16x8 vf[2][4];
#pragma unroll
        for (int mt = 0; mt < 2; ++mt)
#pragma unroll
            for (int kk = 0; kk < 4; ++kk)
                vf[mt][kk] = *(const bf16x8*)(Vb + (size_t)kt * 4096 + (mt * 4 + kk) * 512);

        f32x16 T[2] = {};
        __builtin_amdgcn_s_setprio(1);
#pragma unroll
        for (int kk = 0; kk < 4; ++kk)
#pragma unroll
            for (int mt = 0; mt < 2; ++mt)
                T[mt] = __builtin_amdgcn_mfma_f32_32x32x16_bf16(kf[mt][kk], qf[kk], T[mt], 0, 0, 0);
        __builtin_amdgcn_s_setprio(0);

        // K prefetch for next tile (kf free now; consumed next iteration)
        if (kt < 15) {
#pragma unroll
            for (int mt = 0; mt < 2; ++mt)
#pragma unroll
                for (int kk = 0; kk < 4; ++kk)
                    kf[mt][kk] = *(const bf16x8*)(Kb + ((size_t)(kt + 1) * 2 + mt) * 2048 + kk * 512);
        }

        // flag-gated mask add (wave-uniform branch), then max-free exp2
        unsigned fl = __builtin_amdgcn_readfirstlane(flg[kt]);
        if (fl) {
#pragma unroll
            for (int mt = 0; mt < 2; ++mt)
#pragma unroll
                for (int g = 0; g < 4; ++g) {
                    f32x4 mk = *(const f32x4*)(mrow + kt * 64 + mt * 32 + g * 8);
#pragma unroll
                    for (int c = 0; c < 4; ++c)
                        T[mt][4 * g + c] = fmaf(mk[c], L2E, T[mt][4 * g + c]);
                }
        }
#pragma unroll
        for (int g = 0; g < 4; ++g) {
            float a0 = fexp2(T[0][4 * g + 0]);
            float a1 = fexp2(T[0][4 * g + 1]);
            float a2 = fexp2(T[0][4 * g + 2]);
            float a3 = fexp2(T[0][4 * g + 3]);
            float b0 = fexp2(T[1][4 * g + 0]);
            float b1 = fexp2(T[1][4 * g + 1]);
            float b2 = fexp2(T[1][4 * g + 2]);
            float b3 = fexp2(T[1][4 * g + 3]);
            la0 += (a0 + a1) + (a2 + a3);
            la1 += (b0 + b1) + (b2 + b3);
            T[0][4 * g + 0] = a0; T[0][4 * g + 1] = a1;
            T[0][4 * g + 2] = a2; T[0][4 * g + 3] = a3;
            T[1][4 * g + 0] = b0; T[1][4 * g + 1] = b1;
            T[1][4 * g + 2] = b2; T[1][4 * g + 3] = b3;
        }

        // P frags in-register: pf[kk][j] = P[q=q31][kv = kk*16 + hi*8 + j]
        bf16x8 pf[4];
#pragma unroll
        for (int kk = 0; kk < 4; ++kk) {
            int mt = kk >> 1;
            int gA = (2 * kk) & 3, gB = gA + 1;
            unsigned x0 = cvtpk(T[mt][4 * gA + 0], T[mt][4 * gA + 1]);
            unsigned x1 = cvtpk(T[mt][4 * gA + 2], T[mt][4 * gA + 3]);
            unsigned y0 = cvtpk(T[mt][4 * gB + 0], T[mt][4 * gB + 1]);
            unsigned y1 = cvtpk(T[mt][4 * gB + 2], T[mt][4 * gB + 3]);
            pswap(x0, y0);
            pswap(x1, y1);
            u32x4 packed; packed[0] = x0; packed[1] = x1; packed[2] = y0; packed[3] = y1;
            pf[kk] = __builtin_bit_cast(bf16x8, packed);
        }

        __builtin_amdgcn_s_setprio(1);
#pragma unroll
        for (int kk = 0; kk < 4; ++kk)
#pragma unroll
            for (int mt = 0; mt < 2; ++mt)
                O[mt] = __builtin_amdgcn_mfma_f32_32x32x16_bf16(vf[mt][kk], pf[kk], O[mt], 0, 0, 0);
        __builtin_amdgcn_s_setprio(0);
    }

    // combine via plain coalesced stores (one writer per address)
    float l_acc = la0 + la1;
    l_acc += __shfl_xor(l_acc, 32, 64);
    if (hi == 0)
        lacc[((size_t)z * 32 + b * 16 + h) * 2048 + qw + q31] = l_acc;
    __bf16* Ob = (z ? Op1 : Op0) + (((size_t)(b * 16 + h)) * 2048 + qw + q31) * 64 + hi * 4;
#pragma unroll
    for (int mt = 0; mt < 2; ++mt)
#pragma unroll
        for (int g = 0; g < 4; ++g) {
            bf16x4 o;
#pragma unroll
            for (int c = 0; c < 4; ++c) o[c] = (__bf16)O[mt][4 * g + c];
            *(bf16x4*)(Ob + mt * 32 + g * 8) = o;
        }
}

// normalize: x[b,s,h*64+e] = bf16((Op0+Op1)[b][h][s][e] / (l0+l1)[b][h][s])
__global__ __launch_bounds__(256) void attn_norm(const __bf16* __restrict__ Op0,
                                                 const __bf16* __restrict__ Op1,
                                                 const float* __restrict__ lacc,
                                                 __bf16* __restrict__ x) {
    int idx = blockIdx.x * 256 + threadIdx.x;   // 1,048,576 total
    int b = idx >> 19;
    int rem = idx & 524287;                     // h[4] s[11] e4[4]
    int h = rem >> 15;
    int s = (rem >> 4) & 2047;
    int e0 = (rem & 15) * 4;
    size_t base = (((size_t)(b * 16 + h)) * 2048 + s) * 64 + e0;
    bf16x4 a = *(const bf16x4*)(Op0 + base);
    bf16x4 c = *(const bf16x4*)(Op1 + base);
    size_t li = ((size_t)(b * 16 + h)) * 2048 + s;
    float inv = 1.0f / (lacc[li] + lacc[65536 + li]);
    bf16x4 r;
#pragma unroll
    for (int j = 0; j < 4; ++j)
        r[j] = (__bf16)(((float)a[j] + (float)c[j]) * inv);
    *(bf16x4*)(x + ((size_t)b * 2048 + s) * 1024 + h * 64 + e0) = r;
}

// ---------------- launch ----------------

extern "C" void kernel_launch(void* const* d_in, const int* in_sizes, int n_in,
                              void* d_out, int out_size, void* d_ws, size_t ws_size,
                              hipStream_t stream) {
    const float* q    = (const float*)d_in[0];
    const float* k    = (const float*)d_in[1];
    const float* v    = (const float*)d_in[2];
    const float* mask = (const float*)d_in[3];
    const float* Wq   = (const float*)d_in[4];
    const float* bq   = (const float*)d_in[5];
    const float* Wk   = (const float*)d_in[6];
    const float* bk   = (const float*)d_in[7];
    const float* Wv   = (const float*)d_in[8];
    const float* bv   = (const float*)d_in[9];
    const float* Wo   = (const float*)d_in[10];
    const float* bo   = (const float*)d_in[11];

    char* ws = (char*)d_ws;
    __bf16* qb  = (__bf16*)(ws + (0ull  << 20));   // -> Op0 after gemm_qkv
    __bf16* kb  = (__bf16*)(ws + (8ull  << 20));   // -> Op1 after gemm_qkv
    __bf16* vb  = (__bf16*)(ws + (16ull << 20));   // -> x   after gemm_qkv
    __bf16* w3  = (__bf16*)(ws + (24ull << 20));   // 6 MB
    __bf16* wo  = (__bf16*)(ws + (30ull << 20));   // 2 MB
    __bf16* Qpk = (__bf16*)(ws + (32ull << 20));   // packed Q
    __bf16* Kpk = (__bf16*)(ws + (40ull << 20));   // packed K
    __bf16* Vpk = (__bf16*)(ws + (48ull << 20));   // packed V
    float*  laccp = (float*)(ws + (56ull << 20));                        // 512 KB
    unsigned* flagp = (unsigned*)(ws + (56ull << 20) + (512ull << 10));  // 4 KB
    __bf16* Op0 = qb;
    __bf16* Op1 = kb;
    __bf16* xp  = vb;

    cvt3_kernel<<<dim3(4096, 3), 256, 0, stream>>>(q, k, v, qb, kb, vb);
    pack_w4<<<dim3(16, 16, 4), 256, 0, stream>>>(Wq, Wk, Wv, Wo, w3, wo);
    hipMemsetAsync(flagp, 0, 4096, stream);
    mask_flags<<<8192, 256, 0, stream>>>(mask, flagp);

    gemm_qkv<<<dim3(32, 8, 3), 256, 0, stream>>>(qb, kb, vb, w3, bq, bk, bv,
                                                 Qpk, Kpk, Vpk);

    attn_kernel<<<dim3(1024), 256, 0, stream>>>(Qpk, Kpk, Vpk, mask, flagp,
                                                Op0, Op1, laccp);
    attn_norm<<<4096, 256, 0, stream>>>(Op0, Op1, laccp, xp);

    gemm_out<<<dim3(64, 8), 256, 0, stream>>>(xp, wo, bo, (float*)d_out);
}